// Round 10
// baseline (429.369 us; speedup 1.0000x reference)
//
#include <hip/hip_runtime.h>
#include <hip/hip_bf16.h>

// GIN classifier. R9: gemm1's A-fragment burst moved into ONE volatile inline
// asm block (24x global_load_dwordx4 + s_waitcnt vmcnt(0)) -- the compiler
// cannot sink these, so 24 loads are genuinely in flight per wave. R6-R8
// plain-HIP attempts all compiled to ~2 in flight (VGPR 48-56 proved it).
// Rest unchanged from R8.

#define N_NODES 100000
#define N_EDGES 800000
#define N_GRAPHS 128
#define NB_SCAN 391   // ceil(N_NODES/256)
#define LDP 136       // bf16 LDS row stride (mlp): 2-way bank alias only (free)
#define FLDP 68       // f32 row stride for pool staging

typedef __bf16 bf16x8 __attribute__((ext_vector_type(8)));
typedef float f32x4 __attribute__((ext_vector_type(4)));
typedef unsigned short ushort_t;
typedef unsigned int uint_t;

static __device__ __forceinline__ ushort_t f2b(float f) {
    uint_t u = __builtin_bit_cast(uint_t, f);
    uint_t r = (u + 0x7fffu + ((u >> 16) & 1u)) >> 16;   // RNE
    return (ushort_t)r;
}
static __device__ __forceinline__ float b2f(ushort_t u) {
    return __builtin_bit_cast(float, (uint_t)u << 16);
}

// ------------- all weight transposes in one kernel: Wt[c*K+k] = bf16(W[k*N+c])
__global__ __launch_bounds__(256) void wt_all_k(
        const float* __restrict__ w1a, const float* __restrict__ w1b,
        const float* __restrict__ w2a, const float* __restrict__ w2b,
        const float* __restrict__ w3a, const float* __restrict__ w3b,
        ushort_t* __restrict__ o1a, ushort_t* __restrict__ o1b,
        ushort_t* __restrict__ o2a, ushort_t* __restrict__ o2b,
        ushort_t* __restrict__ o3a, ushort_t* __restrict__ o3b) {
    int t = blockIdx.x * 256 + threadIdx.x;
    const float* W; ushort_t* O; int K, N, i;
    if      (t <  49152) { W = w1a; O = o1a; K = 384; N = 128; i = t; }
    else if (t <  65536) { W = w1b; O = o1b; K = 128; N = 128; i = t - 49152; }
    else if (t <  81920) { W = w2a; O = o2a; K = 128; N = 128; i = t - 65536; }
    else if (t <  98304) { W = w2b; O = o2b; K = 128; N = 128; i = t - 81920; }
    else if (t < 114688) { W = w3a; O = o3a; K = 128; N = 128; i = t - 98304; }
    else if (t < 122880) { W = w3b; O = o3b; K = 128; N = 64;  i = t - 114688; }
    else return;
    int k = i / N, c = i % N;
    O[c * K + k] = f2b(W[i]);
}

// ---------------- D1: C[M,128] = bf16(A fp32 [M,384]) @ Wt ------------------
// One wave per 16-row block, full N=128. The 24 independent A loads live in a
// single volatile asm block with a trailing vmcnt(0): guaranteed burst.
__global__ __launch_bounds__(64, 2) void gemm1_k(const float* __restrict__ A,
                                                 const ushort_t* __restrict__ Wt,
                                                 ushort_t* __restrict__ C) {
    constexpr int K = 384;
    constexpr int EP = 136;                  // epilogue LDS row stride (bf16)
    __shared__ __align__(16) ushort_t El[16 * EP];

    const int lane = threadIdx.x;            // 0..63
    const int row0 = blockIdx.x * 16;        // 6250 blocks -> 100000 rows exact
    const int l15  = lane & 15;
    const int kg   = lane >> 4;

    const float*    pA = A  + (size_t)(row0 + l15) * K + kg * 8;
    const ushort_t* pB = Wt + (size_t)l15 * K + kg * 8;

    // ---- guaranteed burst: 24 loads issued back-to-back, one wait ----
    float4 va[24];
    asm volatile(
        "global_load_dwordx4 %0,  %24, off\n"
        "global_load_dwordx4 %1,  %24, off offset:16\n"
        "global_load_dwordx4 %2,  %24, off offset:128\n"
        "global_load_dwordx4 %3,  %24, off offset:144\n"
        "global_load_dwordx4 %4,  %24, off offset:256\n"
        "global_load_dwordx4 %5,  %24, off offset:272\n"
        "global_load_dwordx4 %6,  %24, off offset:384\n"
        "global_load_dwordx4 %7,  %24, off offset:400\n"
        "global_load_dwordx4 %8,  %24, off offset:512\n"
        "global_load_dwordx4 %9,  %24, off offset:528\n"
        "global_load_dwordx4 %10, %24, off offset:640\n"
        "global_load_dwordx4 %11, %24, off offset:656\n"
        "global_load_dwordx4 %12, %24, off offset:768\n"
        "global_load_dwordx4 %13, %24, off offset:784\n"
        "global_load_dwordx4 %14, %24, off offset:896\n"
        "global_load_dwordx4 %15, %24, off offset:912\n"
        "global_load_dwordx4 %16, %24, off offset:1024\n"
        "global_load_dwordx4 %17, %24, off offset:1040\n"
        "global_load_dwordx4 %18, %24, off offset:1152\n"
        "global_load_dwordx4 %19, %24, off offset:1168\n"
        "global_load_dwordx4 %20, %24, off offset:1280\n"
        "global_load_dwordx4 %21, %24, off offset:1296\n"
        "global_load_dwordx4 %22, %24, off offset:1408\n"
        "global_load_dwordx4 %23, %24, off offset:1424\n"
        "s_waitcnt vmcnt(0)\n"
        : "=&v"(va[0]),  "=&v"(va[1]),  "=&v"(va[2]),  "=&v"(va[3]),
          "=&v"(va[4]),  "=&v"(va[5]),  "=&v"(va[6]),  "=&v"(va[7]),
          "=&v"(va[8]),  "=&v"(va[9]),  "=&v"(va[10]), "=&v"(va[11]),
          "=&v"(va[12]), "=&v"(va[13]), "=&v"(va[14]), "=&v"(va[15]),
          "=&v"(va[16]), "=&v"(va[17]), "=&v"(va[18]), "=&v"(va[19]),
          "=&v"(va[20]), "=&v"(va[21]), "=&v"(va[22]), "=&v"(va[23])
        : "v"(pA)
        : "memory");

    f32x4 acc[8];
    #pragma unroll
    for (int j = 0; j < 8; ++j) acc[j] = f32x4{0.f, 0.f, 0.f, 0.f};

    #pragma unroll
    for (int kk = 0; kk < 12; ++kk) {
        float4 x0 = va[2 * kk], x1 = va[2 * kk + 1];
        bf16x8 af;
        af[0] = (__bf16)x0.x; af[1] = (__bf16)x0.y;
        af[2] = (__bf16)x0.z; af[3] = (__bf16)x0.w;
        af[4] = (__bf16)x1.x; af[5] = (__bf16)x1.y;
        af[6] = (__bf16)x1.z; af[7] = (__bf16)x1.w;
        #pragma unroll
        for (int j = 0; j < 8; ++j) {
            bf16x8 bf = *reinterpret_cast<const bf16x8*>(pB + (size_t)j * 16 * K + kk * 32);
            acc[j] = __builtin_amdgcn_mfma_f32_16x16x32_bf16(af, bf, acc[j], 0, 0, 0);
        }
    }

    // epilogue: stage 16x128 in LDS, full-256B-row coalesced stores
    #pragma unroll
    for (int j = 0; j < 8; ++j)
        #pragma unroll
        for (int q = 0; q < 4; ++q)
            El[(kg * 4 + q) * EP + j * 16 + l15] = f2b(acc[j][q]);
    __syncthreads();                          // single wave: cheap
    #pragma unroll
    for (int p = 0; p < 4; ++p) {
        int r = p * 4 + (lane >> 4);
        *reinterpret_cast<uint4*>(C + (size_t)(row0 + r) * 128 + (lane & 15) * 8) =
            *reinterpret_cast<const uint4*>(&El[r * EP + (lane & 15) * 8]);
    }
}

// ---------------- CSR build ----------------
__global__ __launch_bounds__(256) void hist_k(const int* __restrict__ dst,
                                              int* __restrict__ deg) {
    int e = blockIdx.x * 256 + threadIdx.x;
    if (e < N_EDGES) atomicAdd(&deg[dst[e]], 1);
}

__global__ __launch_bounds__(256) void scan1_k(const int* __restrict__ deg,
                                               int* __restrict__ tmp,
                                               int* __restrict__ bsum) {
    __shared__ int s[256];
    int i = blockIdx.x * 256 + threadIdx.x;
    int t = threadIdx.x;
    s[t] = (i < N_NODES) ? deg[i] : 0;
    __syncthreads();
    for (int off = 1; off < 256; off <<= 1) {
        int v = (t >= off) ? s[t - off] : 0;
        __syncthreads();
        s[t] += v;
        __syncthreads();
    }
    if (i < N_NODES) tmp[i] = s[t];
    if (t == 255) bsum[blockIdx.x] = s[255];
}

__global__ __launch_bounds__(512) void scan2_k(int* __restrict__ bsum) {
    __shared__ int s[512];
    int t = threadIdx.x;
    s[t] = (t < NB_SCAN) ? bsum[t] : 0;
    __syncthreads();
    for (int off = 1; off < 512; off <<= 1) {
        int v = (t >= off) ? s[t - off] : 0;
        __syncthreads();
        s[t] += v;
        __syncthreads();
    }
    if (t < NB_SCAN) bsum[t] = s[t];
}

__global__ __launch_bounds__(256) void scan3_k(const int* __restrict__ tmp,
                                               const int* __restrict__ deg,
                                               const int* __restrict__ bsum,
                                               int* __restrict__ row_start) {
    int i = blockIdx.x * 256 + threadIdx.x;
    if (i >= N_NODES) return;
    int boff = (blockIdx.x > 0) ? bsum[blockIdx.x - 1] : 0;
    row_start[i] = tmp[i] - deg[i] + boff;
}

__global__ __launch_bounds__(256) void fill_k(const int* __restrict__ src,
                                              const int* __restrict__ dst,
                                              int* __restrict__ row_start,
                                              int* __restrict__ csr_src) {
    int e = blockIdx.x * 256 + threadIdx.x;
    if (e >= N_EDGES) return;
    int idx = atomicAdd(&row_start[dst[e]], 1);
    csr_src[idx] = src[e];
}

// ---- gather + BN + ReLU, one wave/node, 4 slots, 2-deep node pipeline ------
__global__ __launch_bounds__(256) void gather_bn_k(
        const ushort_t* __restrict__ Yin,
        const int* __restrict__ csr, const int* __restrict__ rend,
        const int* __restrict__ deg,
        const float* __restrict__ epsp, const float* __restrict__ ba,
        const float* __restrict__ g, const float* __restrict__ be,
        const float* __restrict__ mm, const float* __restrict__ vv,
        ushort_t* __restrict__ H, int nwaves) {
    const int gwid = (blockIdx.x * 256 + threadIdx.x) >> 6;
    const int lane = threadIdx.x & 63;
    const int l15  = lane & 15;
    const int slot = lane >> 4;
    const int c0   = l15 * 8;

    float ep = 1.0f + epsp[0];
    float sc[8], sh[8];
    #pragma unroll
    for (int jj = 0; jj < 8; ++jj) {
        int c = c0 + jj;
        float s = g[c] * rsqrtf(vv[c] + 1e-5f);
        sc[jj] = s;
        sh[jj] = (ba[c] - mm[c]) * s + be[c];
    }

    int node = gwid;
    if (node >= N_NODES) return;
    int end = rend[node], d = deg[node];
    int st = end - d;
    int nlim = (d > 64) ? 64 : d;
    int nb = (lane < nlim) ? csr[st + lane] : 0;

    for (; node < N_NODES; node += nwaves) {
        const int nnode = node + nwaves;
        int nend = 0, nd = 0;
        if (nnode < N_NODES) { nend = rend[nnode]; nd = deg[nnode]; }  // prefetch meta

        uint4 ow = *reinterpret_cast<const uint4*>(Yin + (size_t)node * 128 + c0);

        float acc[8] = {0.f, 0.f, 0.f, 0.f, 0.f, 0.f, 0.f, 0.f};
        for (int j0 = 0; j0 < nlim; j0 += 8) {
            int jA = j0 + slot;
            int jB = j0 + 4 + slot;
            int ia = __shfl(nb, jA & 63);
            int ib = __shfl(nb, jB & 63);
            uint4 wa = *reinterpret_cast<const uint4*>(Yin + (size_t)ia * 128 + c0);
            uint4 wb = *reinterpret_cast<const uint4*>(Yin + (size_t)ib * 128 + c0);
            float fa = (jA < nlim) ? 1.f : 0.f;
            float fb = (jB < nlim) ? 1.f : 0.f;
            uint_t ua[4] = {wa.x, wa.y, wa.z, wa.w};
            uint_t ub[4] = {wb.x, wb.y, wb.z, wb.w};
            #pragma unroll
            for (int p = 0; p < 4; ++p) {
                acc[2 * p]     += fa * b2f((ushort_t)(ua[p] & 0xffff));
                acc[2 * p + 1] += fa * b2f((ushort_t)(ua[p] >> 16));
                acc[2 * p]     += fb * b2f((ushort_t)(ub[p] & 0xffff));
                acc[2 * p + 1] += fb * b2f((ushort_t)(ub[p] >> 16));
            }
        }
        for (int j = st + 64; j < end; ++j) {
            if (slot == 0) {
                int idx = csr[j];
                uint4 w = *reinterpret_cast<const uint4*>(Yin + (size_t)idx * 128 + c0);
                uint_t uw[4] = {w.x, w.y, w.z, w.w};
                #pragma unroll
                for (int p = 0; p < 4; ++p) {
                    acc[2 * p]     += b2f((ushort_t)(uw[p] & 0xffff));
                    acc[2 * p + 1] += b2f((ushort_t)(uw[p] >> 16));
                }
            }
        }

        // prefetch next node's indices (overlaps reduce + BN + store)
        int nst = nend - nd;
        int nnlim = (nd > 64) ? 64 : nd;
        int nb2 = 0;
        if (nnode < N_NODES && lane < nnlim) nb2 = csr[nst + lane];

        #pragma unroll
        for (int jj = 0; jj < 8; ++jj) {
            acc[jj] += __shfl_xor(acc[jj], 16);
            acc[jj] += __shfl_xor(acc[jj], 32);
        }
        uint_t uo[4] = {ow.x, ow.y, ow.z, ow.w};
        ushort_t rr[8];
        #pragma unroll
        for (int p = 0; p < 4; ++p) {
            float o0 = b2f((ushort_t)(uo[p] & 0xffff));
            float o1 = b2f((ushort_t)(uo[p] >> 16));
            float t0 = sc[2 * p] * (ep * o0 + acc[2 * p]) + sh[2 * p];
            float t1 = sc[2 * p + 1] * (ep * o1 + acc[2 * p + 1]) + sh[2 * p + 1];
            rr[2 * p]     = f2b(fmaxf(t0, 0.f));
            rr[2 * p + 1] = f2b(fmaxf(t1, 0.f));
        }
        if (slot == 0) {
            uint4 packed;
            packed.x = (uint_t)rr[0] | ((uint_t)rr[1] << 16);
            packed.y = (uint_t)rr[2] | ((uint_t)rr[3] << 16);
            packed.z = (uint_t)rr[4] | ((uint_t)rr[5] << 16);
            packed.w = (uint_t)rr[6] | ((uint_t)rr[7] << 16);
            *reinterpret_cast<uint4*>(H + (size_t)node * 128 + c0) = packed;
        }

        end = nend; d = nd; st = nst; nlim = nnlim; nb = nb2;
    }
}

// -------- MLP pair: X=relu(H@Wb+bias); TAIL? pool(X) : Yout = X@Wa2 ----------
template<bool TAIL>
__global__ __launch_bounds__(256) void mlp_k(const ushort_t* __restrict__ Hin,
                                             const ushort_t* __restrict__ Wb,
                                             const float* __restrict__ bias1,
                                             const ushort_t* __restrict__ Wa2,
                                             ushort_t* __restrict__ Yout,
                                             const int* __restrict__ batch,
                                             float* __restrict__ pooled, int M) {
    constexpr int BM = 64;
    constexpr int NJ1 = TAIL ? 2 : 4;       // N1 = 64 or 128
    __shared__ ushort_t Hl[BM * LDP];
    __shared__ ushort_t Xl[BM * LDP];       // also f32 pool staging [64][FLDP]
    float* Fl = (float*)Xl;

    const int tid  = threadIdx.x;
    const int lane = tid & 63;
    const int wid  = tid >> 6;
    const int wrow = wid >> 1;
    const int wcol = wid & 1;
    const int l15  = lane & 15;
    const int kg   = lane >> 4;
    const int row0 = blockIdx.x * BM;

    #pragma unroll
    for (int p = 0; p < 4; ++p) {
        int idx = tid + p * 256;
        int r = idx >> 4, c16 = idx & 15;
        int gr = row0 + r;
        if (gr > M - 1) gr = M - 1;
        *reinterpret_cast<uint4*>(&Hl[r * LDP + c16 * 8]) =
            *reinterpret_cast<const uint4*>(Hin + (size_t)gr * 128 + c16 * 8);
    }
    __syncthreads();

    f32x4 acc1[2][NJ1];
    #pragma unroll
    for (int i = 0; i < 2; ++i)
        #pragma unroll
        for (int j = 0; j < NJ1; ++j)
            acc1[i][j] = f32x4{0.f, 0.f, 0.f, 0.f};
    #pragma unroll
    for (int kk = 0; kk < 4; ++kk) {
        bf16x8 a0 = *reinterpret_cast<const bf16x8*>(&Hl[(wrow * 32 + l15) * LDP + kk * 32 + kg * 8]);
        bf16x8 a1 = *reinterpret_cast<const bf16x8*>(&Hl[(wrow * 32 + 16 + l15) * LDP + kk * 32 + kg * 8]);
        #pragma unroll
        for (int j = 0; j < NJ1; ++j) {
            int col = wcol * (16 * NJ1) + j * 16 + l15;
            bf16x8 b = *reinterpret_cast<const bf16x8*>(Wb + (size_t)col * 128 + kk * 32 + kg * 8);
            acc1[0][j] = __builtin_amdgcn_mfma_f32_16x16x32_bf16(a0, b, acc1[0][j], 0, 0, 0);
            acc1[1][j] = __builtin_amdgcn_mfma_f32_16x16x32_bf16(a1, b, acc1[1][j], 0, 0, 0);
        }
    }

    if constexpr (TAIL) {
        #pragma unroll
        for (int i = 0; i < 2; ++i)
            #pragma unroll
            for (int j = 0; j < NJ1; ++j) {
                int col = wcol * 32 + j * 16 + l15;
                float bi = bias1[col];
                #pragma unroll
                for (int q = 0; q < 4; ++q) {
                    int row = wrow * 32 + i * 16 + kg * 4 + q;
                    Fl[row * FLDP + col] = fmaxf(acc1[i][j][q] + bi, 0.f);
                }
            }
        __syncthreads();
        int col = tid & 63;
        int qq  = tid >> 6;
        float a = 0.f;
        int cur = -1;
        for (int rr = 0; rr < 16; ++rr) {
            int r = qq * 16 + rr;
            int gr = row0 + r;
            if (gr >= M) break;
            int b = batch[gr];
            if (b != cur) {
                if (cur >= 0) atomicAdd(&pooled[cur * 64 + col], a);
                a = 0.f;
                cur = b;
            }
            a += Fl[r * FLDP + col];
        }
        if (cur >= 0) atomicAdd(&pooled[cur * 64 + col], a);
    } else {
        #pragma unroll
        for (int i = 0; i < 2; ++i)
            #pragma unroll
            for (int j = 0; j < NJ1; ++j) {
                int col = wcol * 64 + j * 16 + l15;
                float bi = bias1[col];
                #pragma unroll
                for (int q = 0; q < 4; ++q) {
                    int row = wrow * 32 + i * 16 + kg * 4 + q;
                    Xl[row * LDP + col] = f2b(fmaxf(acc1[i][j][q] + bi, 0.f));
                }
            }
        __syncthreads();

        f32x4 acc2[2][4];
        #pragma unroll
        for (int i = 0; i < 2; ++i)
            #pragma unroll
            for (int j = 0; j < 4; ++j)
                acc2[i][j] = f32x4{0.f, 0.f, 0.f, 0.f};
        #pragma unroll
        for (int kk = 0; kk < 4; ++kk) {
            bf16x8 a0 = *reinterpret_cast<const bf16x8*>(&Xl[(wrow * 32 + l15) * LDP + kk * 32 + kg * 8]);
            bf16x8 a1 = *reinterpret_cast<const bf16x8*>(&Xl[(wrow * 32 + 16 + l15) * LDP + kk * 32 + kg * 8]);
            #pragma unroll
            for (int j = 0; j < 4; ++j) {
                int col = wcol * 64 + j * 16 + l15;
                bf16x8 b = *reinterpret_cast<const bf16x8*>(Wa2 + (size_t)col * 128 + kk * 32 + kg * 8);
                acc2[0][j] = __builtin_amdgcn_mfma_f32_16x16x32_bf16(a0, b, acc2[0][j], 0, 0, 0);
                acc2[1][j] = __builtin_amdgcn_mfma_f32_16x16x32_bf16(a1, b, acc2[1][j], 0, 0, 0);
            }
        }
        #pragma unroll
        for (int i = 0; i < 2; ++i)
            #pragma unroll
            for (int j = 0; j < 4; ++j) {
                int col = wcol * 64 + j * 16 + l15;
                #pragma unroll
                for (int q = 0; q < 4; ++q) {
                    int row = wrow * 32 + i * 16 + kg * 4 + q;
                    Hl[row * LDP + col] = f2b(acc2[i][j][q]);
                }
            }
        __syncthreads();
        #pragma unroll
        for (int p = 0; p < 4; ++p) {
            int idx = tid + p * 256;
            int r = idx >> 4, c16 = idx & 15;
            int gr = row0 + r;
            if (gr < M)
                *reinterpret_cast<uint4*>(Yout + (size_t)gr * 128 + c16 * 8) =
                    *reinterpret_cast<const uint4*>(&Hl[r * LDP + c16 * 8]);
        }
    }
}

// ---------------- classifier ----------------
__global__ __launch_bounds__(256) void classifier_k(const float* __restrict__ pooled,
                                                    const float* __restrict__ wc,
                                                    const float* __restrict__ bc,
                                                    float* __restrict__ out) {
    int t = threadIdx.x;
    int gidx = t >> 1, c = t & 1;
    float s = bc[c];
    #pragma unroll
    for (int k = 0; k < 64; ++k)
        s += pooled[gidx * 64 + k] * wc[k * 2 + c];
    out[gidx * 2 + c] = s;
}

extern "C" void kernel_launch(void* const* d_in, const int* in_sizes, int n_in,
                              void* d_out, int out_size, void* d_ws, size_t ws_size,
                              hipStream_t stream) {
    const float* x     = (const float*)d_in[0];
    const int*   ei    = (const int*)d_in[1];
    const int*   src   = ei;
    const int*   dst   = ei + N_EDGES;
    const int*   batch = (const int*)d_in[2];
    const float* eps1 = (const float*)d_in[3];
    const float* w1a  = (const float*)d_in[4];
    const float* b1a  = (const float*)d_in[5];
    const float* g1   = (const float*)d_in[6];
    const float* be1  = (const float*)d_in[7];
    const float* m1   = (const float*)d_in[8];
    const float* v1   = (const float*)d_in[9];
    const float* w1b  = (const float*)d_in[10];
    const float* b1b  = (const float*)d_in[11];
    const float* eps2 = (const float*)d_in[12];
    const float* w2a  = (const float*)d_in[13];
    const float* b2a  = (const float*)d_in[14];
    const float* g2   = (const float*)d_in[15];
    const float* be2  = (const float*)d_in[16];
    const float* m2   = (const float*)d_in[17];
    const float* v2   = (const float*)d_in[18];
    const float* w2b  = (const float*)d_in[19];
    const float* b2b  = (const float*)d_in[20];
    const float* eps3 = (const float*)d_in[21];
    const float* w3a  = (const float*)d_in[22];
    const float* b3a  = (const float*)d_in[23];
    const float* g3   = (const float*)d_in[24];
    const float* be3  = (const float*)d_in[25];
    const float* m3   = (const float*)d_in[26];
    const float* v3   = (const float*)d_in[27];
    const float* w3b  = (const float*)d_in[28];
    const float* b3b  = (const float*)d_in[29];
    const float* wc   = (const float*)d_in[30];
    const float* bc   = (const float*)d_in[31];
    float* out = (float*)d_out;

    // workspace layout
    ushort_t* Y = (ushort_t*)d_ws;             // [100000,128] bf16
    ushort_t* H = Y + 12800000;                // [100000,128] bf16
    ushort_t* wt1a = H + 12800000;             // 384*128
    ushort_t* wt1b = wt1a + 49152;             // 128*128
    ushort_t* wt2a = wt1b + 16384;
    ushort_t* wt2b = wt2a + 16384;
    ushort_t* wt3a = wt2b + 16384;
    ushort_t* wt3b = wt3a + 16384;             // 64*128
    float* pooled = (float*)(wt3b + 8192);     // [128,64]
    int* ideg = (int*)(pooled + 8192);         // [100000]
    int* irow = ideg + N_NODES;
    int* itmp = irow + N_NODES;
    int* icsr = itmp + N_NODES;                // [800000]
    int* ibsum = icsr + N_EDGES;               // [391]

    const int M = N_NODES;
    const int gGemm = (M + 63) / 64;           // 1563
    const int gG1   = 6250;                    // one 16-row wave per block
    const int gEdge = (N_EDGES + 255) / 256;   // 3125
    const int gNode = NB_SCAN;                 // 391
    const int gGath = 2048;                    // 8192 waves
    const int nwaves = gGath * 4;

    // ---- all weight transposes (one dispatch) ----
    wt_all_k<<<480, 256, 0, stream>>>(w1a, w1b, w2a, w2b, w3a, w3b,
                                      wt1a, wt1b, wt2a, wt2b, wt3a, wt3b);

    // ---- build CSR ----
    hipMemsetAsync(ideg, 0, N_NODES * sizeof(int), stream);
    hist_k<<<gEdge, 256, 0, stream>>>(dst, ideg);
    scan1_k<<<gNode, 256, 0, stream>>>(ideg, itmp, ibsum);
    scan2_k<<<1, 512, 0, stream>>>(ibsum);
    scan3_k<<<gNode, 256, 0, stream>>>(itmp, ideg, ibsum, irow);
    fill_k<<<gEdge, 256, 0, stream>>>(src, dst, irow, icsr);
    hipMemsetAsync(pooled, 0, (size_t)N_GRAPHS * 64 * sizeof(float), stream);

    // ---- D1: Y1 = x @ w1a ----
    gemm1_k<<<gG1, 64, 0, stream>>>(x, wt1a, Y);

    // ---- layer 1 ----
    gather_bn_k<<<gGath, 256, 0, stream>>>(Y, icsr, irow, ideg, eps1, b1a, g1, be1, m1, v1, H, nwaves);
    mlp_k<false><<<gGemm, 256, 0, stream>>>(H, wt1b, b1b, wt2a, Y, nullptr, nullptr, M);

    // ---- layer 2 ----
    gather_bn_k<<<gGath, 256, 0, stream>>>(Y, icsr, irow, ideg, eps2, b2a, g2, be2, m2, v2, H, nwaves);
    mlp_k<false><<<gGemm, 256, 0, stream>>>(H, wt2b, b2b, wt3a, Y, nullptr, nullptr, M);

    // ---- layer 3 ----
    gather_bn_k<<<gGath, 256, 0, stream>>>(Y, icsr, irow, ideg, eps3, b3a, g3, be3, m3, v3, H, nwaves);
    mlp_k<true><<<gGemm, 256, 0, stream>>>(H, wt3b, b3b, nullptr, nullptr, batch, pooled, M);

    // ---- classifier ----
    classifier_k<<<1, 256, 0, stream>>>(pooled, wc, bc, out);
}

// Round 11
// 373.044 us; speedup vs baseline: 1.1510x; 1.1510x over previous
//
#include <hip/hip_runtime.h>
#include <hip/hip_bf16.h>

// GIN classifier. R10: revert gemm1 to R4's proven block GEMM (90-98 us
// measured; wave-tile variants R6-R9 all ~120). Fuse CSR histogram into the
// gemm1 dispatch (independent blocks), memsets into wt_all, scan2+scan3 into
// scan23. 16 -> 12 dispatches. gather/mlp unchanged (R8 pipelined gather).

#define N_NODES 100000
#define N_EDGES 800000
#define N_GRAPHS 128
#define NB_SCAN 391   // ceil(N_NODES/256)
#define LDP 136       // bf16 LDS row stride: 2-way bank alias only (free)
#define FLDP 68       // f32 row stride for pool staging
#define G1_BLOCKS 1563
#define HIST_BLOCKS 782   // 782*1024 >= 800000

typedef __bf16 bf16x8 __attribute__((ext_vector_type(8)));
typedef float f32x4 __attribute__((ext_vector_type(4)));
typedef unsigned short ushort_t;
typedef unsigned int uint_t;

static __device__ __forceinline__ ushort_t f2b(float f) {
    uint_t u = __builtin_bit_cast(uint_t, f);
    uint_t r = (u + 0x7fffu + ((u >> 16) & 1u)) >> 16;   // RNE
    return (ushort_t)r;
}
static __device__ __forceinline__ float b2f(ushort_t u) {
    return __builtin_bit_cast(float, (uint_t)u << 16);
}

// ---- weight transposes + zero ideg + zero pooled, one dispatch -------------
__global__ __launch_bounds__(256) void wt_all_k(
        const float* __restrict__ w1a, const float* __restrict__ w1b,
        const float* __restrict__ w2a, const float* __restrict__ w2b,
        const float* __restrict__ w3a, const float* __restrict__ w3b,
        ushort_t* __restrict__ o1a, ushort_t* __restrict__ o1b,
        ushort_t* __restrict__ o2a, ushort_t* __restrict__ o2b,
        ushort_t* __restrict__ o3a, ushort_t* __restrict__ o3b,
        int* __restrict__ ideg, float* __restrict__ pooled) {
    int t = blockIdx.x * 256 + threadIdx.x;
    if (t < 122880) {
        const float* W; ushort_t* O; int K, N, i;
        if      (t <  49152) { W = w1a; O = o1a; K = 384; N = 128; i = t; }
        else if (t <  65536) { W = w1b; O = o1b; K = 128; N = 128; i = t - 49152; }
        else if (t <  81920) { W = w2a; O = o2a; K = 128; N = 128; i = t - 65536; }
        else if (t <  98304) { W = w2b; O = o2b; K = 128; N = 128; i = t - 81920; }
        else if (t < 114688) { W = w3a; O = o3a; K = 128; N = 128; i = t - 98304; }
        else                 { W = w3b; O = o3b; K = 128; N = 64;  i = t - 114688; }
        int k = i / N, c = i % N;
        O[c * K + k] = f2b(W[i]);
    } else if (t < 222880) {
        ideg[t - 122880] = 0;
    } else if (t < 231072) {
        pooled[t - 222880] = 0.f;
    }
}

// ---- mega dispatch: blocks [0,1563) = gemm1 (R4 block structure, proven);
//      blocks [1563, 2345) = CSR histogram (independent data) ---------------
__global__ __launch_bounds__(256) void gemm1_hist_k(const float* __restrict__ A,
                                                    const ushort_t* __restrict__ Wt,
                                                    ushort_t* __restrict__ C, int M,
                                                    const int* __restrict__ dst,
                                                    int* __restrict__ deg) {
    __shared__ ushort_t Al[64 * LDP];

    if (blockIdx.x >= G1_BLOCKS) {
        // ---- histogram role ----
        int b = blockIdx.x - G1_BLOCKS;
        int e0 = b * 1024 + threadIdx.x;
        #pragma unroll
        for (int p = 0; p < 4; ++p) {
            int e = e0 + p * 256;
            if (e < N_EDGES) atomicAdd(&deg[dst[e]], 1);
        }
        return;
    }

    // ---- gemm1 role: C[M,128] = bf16(A[M,384]) @ Wt, BM=64, BK=128 ----
    constexpr int K = 384;
    const int tid  = threadIdx.x;
    const int lane = tid & 63;
    const int wid  = tid >> 6;
    const int wrow = wid >> 1;
    const int wcol = wid & 1;
    const int l15  = lane & 15;
    const int kg   = lane >> 4;
    const int row0 = blockIdx.x * 64;

    f32x4 acc[2][4];
    #pragma unroll
    for (int i = 0; i < 2; ++i)
        #pragma unroll
        for (int j = 0; j < 4; ++j)
            acc[i][j] = f32x4{0.f, 0.f, 0.f, 0.f};

    const int r  = tid >> 2;                // staging row 0..63
    const int cc = (tid & 3) * 32;          // staging col chunk (f32 units)

    for (int k0 = 0; k0 < K; k0 += 128) {
        __syncthreads();
        {
            int gr = row0 + r;
            if (gr > M - 1) gr = M - 1;
            const float* pA = A + (size_t)gr * K + k0 + cc;
            float4 v[8];
            #pragma unroll
            for (int p = 0; p < 8; ++p)
                v[p] = *reinterpret_cast<const float4*>(pA + p * 4);
            uint_t u[16];
            #pragma unroll
            for (int p = 0; p < 8; ++p) {
                u[2 * p]     = (uint_t)f2b(v[p].x) | ((uint_t)f2b(v[p].y) << 16);
                u[2 * p + 1] = (uint_t)f2b(v[p].z) | ((uint_t)f2b(v[p].w) << 16);
            }
            uint4* dstp = reinterpret_cast<uint4*>(&Al[r * LDP + cc]);
            dstp[0] = make_uint4(u[0], u[1], u[2], u[3]);
            dstp[1] = make_uint4(u[4], u[5], u[6], u[7]);
            dstp[2] = make_uint4(u[8], u[9], u[10], u[11]);
            dstp[3] = make_uint4(u[12], u[13], u[14], u[15]);
        }
        __syncthreads();

        #pragma unroll
        for (int kk = 0; kk < 4; ++kk) {
            bf16x8 a0 = *reinterpret_cast<const bf16x8*>(&Al[(wrow * 32 + l15) * LDP + kk * 32 + kg * 8]);
            bf16x8 a1 = *reinterpret_cast<const bf16x8*>(&Al[(wrow * 32 + 16 + l15) * LDP + kk * 32 + kg * 8]);
            #pragma unroll
            for (int j = 0; j < 4; ++j) {
                int col = wcol * 64 + j * 16 + l15;
                bf16x8 b = *reinterpret_cast<const bf16x8*>(Wt + (size_t)col * K + k0 + kk * 32 + kg * 8);
                acc[0][j] = __builtin_amdgcn_mfma_f32_16x16x32_bf16(a0, b, acc[0][j], 0, 0, 0);
                acc[1][j] = __builtin_amdgcn_mfma_f32_16x16x32_bf16(a1, b, acc[1][j], 0, 0, 0);
            }
        }
    }

    // epilogue: stage bf16 rows in LDS, full-line coalesced store
    __syncthreads();
    #pragma unroll
    for (int i = 0; i < 2; ++i)
        #pragma unroll
        for (int j = 0; j < 4; ++j) {
            int col = wcol * 64 + j * 16 + l15;
            #pragma unroll
            for (int q = 0; q < 4; ++q) {
                int row = wrow * 32 + i * 16 + kg * 4 + q;
                Al[row * LDP + col] = f2b(acc[i][j][q]);
            }
        }
    __syncthreads();
    #pragma unroll
    for (int p = 0; p < 4; ++p) {
        int idx = tid + p * 256;
        int rr = idx >> 4, c16 = idx & 15;
        int gr = row0 + rr;
        if (gr < M)
            *reinterpret_cast<uint4*>(C + (size_t)gr * 128 + c16 * 8) =
                *reinterpret_cast<const uint4*>(&Al[rr * LDP + c16 * 8]);
    }
}

// ---------------- CSR scan chain ----------------
__global__ __launch_bounds__(256) void scan1_k(const int* __restrict__ deg,
                                               int* __restrict__ tmp,
                                               int* __restrict__ bsum) {
    __shared__ int s[256];
    int i = blockIdx.x * 256 + threadIdx.x;
    int t = threadIdx.x;
    s[t] = (i < N_NODES) ? deg[i] : 0;
    __syncthreads();
    for (int off = 1; off < 256; off <<= 1) {
        int v = (t >= off) ? s[t - off] : 0;
        __syncthreads();
        s[t] += v;
        __syncthreads();
    }
    if (i < N_NODES) tmp[i] = s[t];
    if (t == 255) bsum[blockIdx.x] = s[255];
}

// fused scan2+scan3: each block reduces its own bsum prefix (<=390 ints, L2)
__global__ __launch_bounds__(256) void scan23_k(const int* __restrict__ tmp,
                                                const int* __restrict__ deg,
                                                const int* __restrict__ bsum,
                                                int* __restrict__ row_start) {
    __shared__ int sb[256];
    int t = threadIdx.x;
    int partial = 0;
    for (int i = t; i < (int)blockIdx.x; i += 256) partial += bsum[i];
    sb[t] = partial;
    __syncthreads();
    for (int off = 128; off > 0; off >>= 1) {
        if (t < off) sb[t] += sb[t + off];
        __syncthreads();
    }
    int boff = sb[0];
    int i = blockIdx.x * 256 + t;
    if (i < N_NODES) row_start[i] = tmp[i] - deg[i] + boff;
}

__global__ __launch_bounds__(256) void fill_k(const int* __restrict__ src,
                                              const int* __restrict__ dst,
                                              int* __restrict__ row_start,
                                              int* __restrict__ csr_src) {
    int e = blockIdx.x * 256 + threadIdx.x;
    if (e >= N_EDGES) return;
    int idx = atomicAdd(&row_start[dst[e]], 1);
    csr_src[idx] = src[e];
}

// ---- gather + BN + ReLU, one wave/node, 4 slots, 2-deep node pipeline ------
__global__ __launch_bounds__(256) void gather_bn_k(
        const ushort_t* __restrict__ Yin,
        const int* __restrict__ csr, const int* __restrict__ rend,
        const int* __restrict__ deg,
        const float* __restrict__ epsp, const float* __restrict__ ba,
        const float* __restrict__ g, const float* __restrict__ be,
        const float* __restrict__ mm, const float* __restrict__ vv,
        ushort_t* __restrict__ H, int nwaves) {
    const int gwid = (blockIdx.x * 256 + threadIdx.x) >> 6;
    const int lane = threadIdx.x & 63;
    const int l15  = lane & 15;
    const int slot = lane >> 4;
    const int c0   = l15 * 8;

    float ep = 1.0f + epsp[0];
    float sc[8], sh[8];
    #pragma unroll
    for (int jj = 0; jj < 8; ++jj) {
        int c = c0 + jj;
        float s = g[c] * rsqrtf(vv[c] + 1e-5f);
        sc[jj] = s;
        sh[jj] = (ba[c] - mm[c]) * s + be[c];
    }

    int node = gwid;
    if (node >= N_NODES) return;
    int end = rend[node], d = deg[node];
    int st = end - d;
    int nlim = (d > 64) ? 64 : d;
    int nb = (lane < nlim) ? csr[st + lane] : 0;

    for (; node < N_NODES; node += nwaves) {
        const int nnode = node + nwaves;
        int nend = 0, nd = 0;
        if (nnode < N_NODES) { nend = rend[nnode]; nd = deg[nnode]; }  // prefetch meta

        uint4 ow = *reinterpret_cast<const uint4*>(Yin + (size_t)node * 128 + c0);

        float acc[8] = {0.f, 0.f, 0.f, 0.f, 0.f, 0.f, 0.f, 0.f};
        for (int j0 = 0; j0 < nlim; j0 += 8) {
            int jA = j0 + slot;
            int jB = j0 + 4 + slot;
            int ia = __shfl(nb, jA & 63);
            int ib = __shfl(nb, jB & 63);
            uint4 wa = *reinterpret_cast<const uint4*>(Yin + (size_t)ia * 128 + c0);
            uint4 wb = *reinterpret_cast<const uint4*>(Yin + (size_t)ib * 128 + c0);
            float fa = (jA < nlim) ? 1.f : 0.f;
            float fb = (jB < nlim) ? 1.f : 0.f;
            uint_t ua[4] = {wa.x, wa.y, wa.z, wa.w};
            uint_t ub[4] = {wb.x, wb.y, wb.z, wb.w};
            #pragma unroll
            for (int p = 0; p < 4; ++p) {
                acc[2 * p]     += fa * b2f((ushort_t)(ua[p] & 0xffff));
                acc[2 * p + 1] += fa * b2f((ushort_t)(ua[p] >> 16));
                acc[2 * p]     += fb * b2f((ushort_t)(ub[p] & 0xffff));
                acc[2 * p + 1] += fb * b2f((ushort_t)(ub[p] >> 16));
            }
        }
        for (int j = st + 64; j < end; ++j) {
            if (slot == 0) {
                int idx = csr[j];
                uint4 w = *reinterpret_cast<const uint4*>(Yin + (size_t)idx * 128 + c0);
                uint_t uw[4] = {w.x, w.y, w.z, w.w};
                #pragma unroll
                for (int p = 0; p < 4; ++p) {
                    acc[2 * p]     += b2f((ushort_t)(uw[p] & 0xffff));
                    acc[2 * p + 1] += b2f((ushort_t)(uw[p] >> 16));
                }
            }
        }

        // prefetch next node's indices (overlaps reduce + BN + store)
        int nst = nend - nd;
        int nnlim = (nd > 64) ? 64 : nd;
        int nb2 = 0;
        if (nnode < N_NODES && lane < nnlim) nb2 = csr[nst + lane];

        #pragma unroll
        for (int jj = 0; jj < 8; ++jj) {
            acc[jj] += __shfl_xor(acc[jj], 16);
            acc[jj] += __shfl_xor(acc[jj], 32);
        }
        uint_t uo[4] = {ow.x, ow.y, ow.z, ow.w};
        ushort_t rr[8];
        #pragma unroll
        for (int p = 0; p < 4; ++p) {
            float o0 = b2f((ushort_t)(uo[p] & 0xffff));
            float o1 = b2f((ushort_t)(uo[p] >> 16));
            float t0 = sc[2 * p] * (ep * o0 + acc[2 * p]) + sh[2 * p];
            float t1 = sc[2 * p + 1] * (ep * o1 + acc[2 * p + 1]) + sh[2 * p + 1];
            rr[2 * p]     = f2b(fmaxf(t0, 0.f));
            rr[2 * p + 1] = f2b(fmaxf(t1, 0.f));
        }
        if (slot == 0) {
            uint4 packed;
            packed.x = (uint_t)rr[0] | ((uint_t)rr[1] << 16);
            packed.y = (uint_t)rr[2] | ((uint_t)rr[3] << 16);
            packed.z = (uint_t)rr[4] | ((uint_t)rr[5] << 16);
            packed.w = (uint_t)rr[6] | ((uint_t)rr[7] << 16);
            *reinterpret_cast<uint4*>(H + (size_t)node * 128 + c0) = packed;
        }

        end = nend; d = nd; st = nst; nlim = nnlim; nb = nb2;
    }
}

// -------- MLP pair: X=relu(H@Wb+bias); TAIL? pool(X) : Yout = X@Wa2 ----------
template<bool TAIL>
__global__ __launch_bounds__(256) void mlp_k(const ushort_t* __restrict__ Hin,
                                             const ushort_t* __restrict__ Wb,
                                             const float* __restrict__ bias1,
                                             const ushort_t* __restrict__ Wa2,
                                             ushort_t* __restrict__ Yout,
                                             const int* __restrict__ batch,
                                             float* __restrict__ pooled, int M) {
    constexpr int BM = 64;
    constexpr int NJ1 = TAIL ? 2 : 4;       // N1 = 64 or 128
    __shared__ ushort_t Hl[BM * LDP];
    __shared__ ushort_t Xl[BM * LDP];       // also f32 pool staging [64][FLDP]
    float* Fl = (float*)Xl;

    const int tid  = threadIdx.x;
    const int lane = tid & 63;
    const int wid  = tid >> 6;
    const int wrow = wid >> 1;
    const int wcol = wid & 1;
    const int l15  = lane & 15;
    const int kg   = lane >> 4;
    const int row0 = blockIdx.x * BM;

    #pragma unroll
    for (int p = 0; p < 4; ++p) {
        int idx = tid + p * 256;
        int r = idx >> 4, c16 = idx & 15;
        int gr = row0 + r;
        if (gr > M - 1) gr = M - 1;
        *reinterpret_cast<uint4*>(&Hl[r * LDP + c16 * 8]) =
            *reinterpret_cast<const uint4*>(Hin + (size_t)gr * 128 + c16 * 8);
    }
    __syncthreads();

    f32x4 acc1[2][NJ1];
    #pragma unroll
    for (int i = 0; i < 2; ++i)
        #pragma unroll
        for (int j = 0; j < NJ1; ++j)
            acc1[i][j] = f32x4{0.f, 0.f, 0.f, 0.f};
    #pragma unroll
    for (int kk = 0; kk < 4; ++kk) {
        bf16x8 a0 = *reinterpret_cast<const bf16x8*>(&Hl[(wrow * 32 + l15) * LDP + kk * 32 + kg * 8]);
        bf16x8 a1 = *reinterpret_cast<const bf16x8*>(&Hl[(wrow * 32 + 16 + l15) * LDP + kk * 32 + kg * 8]);
        #pragma unroll
        for (int j = 0; j < NJ1; ++j) {
            int col = wcol * (16 * NJ1) + j * 16 + l15;
            bf16x8 b = *reinterpret_cast<const bf16x8*>(Wb + (size_t)col * 128 + kk * 32 + kg * 8);
            acc1[0][j] = __builtin_amdgcn_mfma_f32_16x16x32_bf16(a0, b, acc1[0][j], 0, 0, 0);
            acc1[1][j] = __builtin_amdgcn_mfma_f32_16x16x32_bf16(a1, b, acc1[1][j], 0, 0, 0);
        }
    }

    if constexpr (TAIL) {
        #pragma unroll
        for (int i = 0; i < 2; ++i)
            #pragma unroll
            for (int j = 0; j < NJ1; ++j) {
                int col = wcol * 32 + j * 16 + l15;
                float bi = bias1[col];
                #pragma unroll
                for (int q = 0; q < 4; ++q) {
                    int row = wrow * 32 + i * 16 + kg * 4 + q;
                    Fl[row * FLDP + col] = fmaxf(acc1[i][j][q] + bi, 0.f);
                }
            }
        __syncthreads();
        int col = tid & 63;
        int qq  = tid >> 6;
        float a = 0.f;
        int cur = -1;
        for (int rr = 0; rr < 16; ++rr) {
            int r = qq * 16 + rr;
            int gr = row0 + r;
            if (gr >= M) break;
            int b = batch[gr];
            if (b != cur) {
                if (cur >= 0) atomicAdd(&pooled[cur * 64 + col], a);
                a = 0.f;
                cur = b;
            }
            a += Fl[r * FLDP + col];
        }
        if (cur >= 0) atomicAdd(&pooled[cur * 64 + col], a);
    } else {
        #pragma unroll
        for (int i = 0; i < 2; ++i)
            #pragma unroll
            for (int j = 0; j < NJ1; ++j) {
                int col = wcol * 64 + j * 16 + l15;
                float bi = bias1[col];
                #pragma unroll
                for (int q = 0; q < 4; ++q) {
                    int row = wrow * 32 + i * 16 + kg * 4 + q;
                    Xl[row * LDP + col] = f2b(fmaxf(acc1[i][j][q] + bi, 0.f));
                }
            }
        __syncthreads();

        f32x4 acc2[2][4];
        #pragma unroll
        for (int i = 0; i < 2; ++i)
            #pragma unroll
            for (int j = 0; j < 4; ++j)
                acc2[i][j] = f32x4{0.f, 0.f, 0.f, 0.f};
        #pragma unroll
        for (int kk = 0; kk < 4; ++kk) {
            bf16x8 a0 = *reinterpret_cast<const bf16x8*>(&Xl[(wrow * 32 + l15) * LDP + kk * 32 + kg * 8]);
            bf16x8 a1 = *reinterpret_cast<const bf16x8*>(&Xl[(wrow * 32 + 16 + l15) * LDP + kk * 32 + kg * 8]);
            #pragma unroll
            for (int j = 0; j < 4; ++j) {
                int col = wcol * 64 + j * 16 + l15;
                bf16x8 b = *reinterpret_cast<const bf16x8*>(Wa2 + (size_t)col * 128 + kk * 32 + kg * 8);
                acc2[0][j] = __builtin_amdgcn_mfma_f32_16x16x32_bf16(a0, b, acc2[0][j], 0, 0, 0);
                acc2[1][j] = __builtin_amdgcn_mfma_f32_16x16x32_bf16(a1, b, acc2[1][j], 0, 0, 0);
            }
        }
        #pragma unroll
        for (int i = 0; i < 2; ++i)
            #pragma unroll
            for (int j = 0; j < 4; ++j) {
                int col = wcol * 64 + j * 16 + l15;
                #pragma unroll
                for (int q = 0; q < 4; ++q) {
                    int row = wrow * 32 + i * 16 + kg * 4 + q;
                    Hl[row * LDP + col] = f2b(acc2[i][j][q]);
                }
            }
        __syncthreads();
        #pragma unroll
        for (int p = 0; p < 4; ++p) {
            int idx = tid + p * 256;
            int r = idx >> 4, c16 = idx & 15;
            int gr = row0 + r;
            if (gr < M)
                *reinterpret_cast<uint4*>(Yout + (size_t)gr * 128 + c16 * 8) =
                    *reinterpret_cast<const uint4*>(&Hl[r * LDP + c16 * 8]);
        }
    }
}

// ---------------- classifier ----------------
__global__ __launch_bounds__(256) void classifier_k(const float* __restrict__ pooled,
                                                    const float* __restrict__ wc,
                                                    const float* __restrict__ bc,
                                                    float* __restrict__ out) {
    int t = threadIdx.x;
    int gidx = t >> 1, c = t & 1;
    float s = bc[c];
    #pragma unroll
    for (int k = 0; k < 64; ++k)
        s += pooled[gidx * 64 + k] * wc[k * 2 + c];
    out[gidx * 2 + c] = s;
}

extern "C" void kernel_launch(void* const* d_in, const int* in_sizes, int n_in,
                              void* d_out, int out_size, void* d_ws, size_t ws_size,
                              hipStream_t stream) {
    const float* x     = (const float*)d_in[0];
    const int*   ei    = (const int*)d_in[1];
    const int*   src   = ei;
    const int*   dst   = ei + N_EDGES;
    const int*   batch = (const int*)d_in[2];
    const float* eps1 = (const float*)d_in[3];
    const float* w1a  = (const float*)d_in[4];
    const float* b1a  = (const float*)d_in[5];
    const float* g1   = (const float*)d_in[6];
    const float* be1  = (const float*)d_in[7];
    const float* m1   = (const float*)d_in[8];
    const float* v1   = (const float*)d_in[9];
    const float* w1b  = (const float*)d_in[10];
    const float* b1b  = (const float*)d_in[11];
    const float* eps2 = (const float*)d_in[12];
    const float* w2a  = (const float*)d_in[13];
    const float* b2a  = (const float*)d_in[14];
    const float* g2   = (const float*)d_in[15];
    const float* be2  = (const float*)d_in[16];
    const float* m2   = (const float*)d_in[17];
    const float* v2   = (const float*)d_in[18];
    const float* w2b  = (const float*)d_in[19];
    const float* b2b  = (const float*)d_in[20];
    const float* eps3 = (const float*)d_in[21];
    const float* w3a  = (const float*)d_in[22];
    const float* b3a  = (const float*)d_in[23];
    const float* g3   = (const float*)d_in[24];
    const float* be3  = (const float*)d_in[25];
    const float* m3   = (const float*)d_in[26];
    const float* v3   = (const float*)d_in[27];
    const float* w3b  = (const float*)d_in[28];
    const float* b3b  = (const float*)d_in[29];
    const float* wc   = (const float*)d_in[30];
    const float* bc   = (const float*)d_in[31];
    float* out = (float*)d_out;

    // workspace layout
    ushort_t* Y = (ushort_t*)d_ws;             // [100000,128] bf16
    ushort_t* H = Y + 12800000;                // [100000,128] bf16
    ushort_t* wt1a = H + 12800000;             // 384*128
    ushort_t* wt1b = wt1a + 49152;             // 128*128
    ushort_t* wt2a = wt1b + 16384;
    ushort_t* wt2b = wt2a + 16384;
    ushort_t* wt3a = wt2b + 16384;
    ushort_t* wt3b = wt3a + 16384;             // 64*128
    float* pooled = (float*)(wt3b + 8192);     // [128,64]
    int* ideg = (int*)(pooled + 8192);         // [100000]
    int* irow = ideg + N_NODES;
    int* itmp = irow + N_NODES;
    int* icsr = itmp + N_NODES;                // [800000]
    int* ibsum = icsr + N_EDGES;               // [391]

    const int M = N_NODES;
    const int gGemm = (M + 63) / 64;           // 1563
    const int gEdge = (N_EDGES + 255) / 256;   // 3125
    const int gNode = NB_SCAN;                 // 391
    const int gGath = 2048;                    // 8192 waves
    const int nwaves = gGath * 4;

    // ---- 1: weight transposes + zero ideg + zero pooled ----
    wt_all_k<<<903, 256, 0, stream>>>(w1a, w1b, w2a, w2b, w3a, w3b,
                                      wt1a, wt1b, wt2a, wt2b, wt3a, wt3b,
                                      ideg, pooled);

    // ---- 2: gemm1 + histogram (independent roles, one dispatch) ----
    gemm1_hist_k<<<G1_BLOCKS + HIST_BLOCKS, 256, 0, stream>>>(x, wt1a, Y, M, dst, ideg);

    // ---- 3-5: scan chain + fill ----
    scan1_k<<<gNode, 256, 0, stream>>>(ideg, itmp, ibsum);
    scan23_k<<<gNode, 256, 0, stream>>>(itmp, ideg, ibsum, irow);
    fill_k<<<gEdge, 256, 0, stream>>>(src, dst, irow, icsr);

    // ---- layer 1 ----
    gather_bn_k<<<gGath, 256, 0, stream>>>(Y, icsr, irow, ideg, eps1, b1a, g1, be1, m1, v1, H, nwaves);
    mlp_k<false><<<gGemm, 256, 0, stream>>>(H, wt1b, b1b, wt2a, Y, nullptr, nullptr, M);

    // ---- layer 2 ----
    gather_bn_k<<<gGath, 256, 0, stream>>>(Y, icsr, irow, ideg, eps2, b2a, g2, be2, m2, v2, H, nwaves);
    mlp_k<false><<<gGemm, 256, 0, stream>>>(H, wt2b, b2b, wt3a, Y, nullptr, nullptr, M);

    // ---- layer 3 ----
    gather_bn_k<<<gGath, 256, 0, stream>>>(Y, icsr, irow, ideg, eps3, b3a, g3, be3, m3, v3, H, nwaves);
    mlp_k<true><<<gGemm, 256, 0, stream>>>(H, wt3b, b3b, nullptr, nullptr, batch, pooled, M);

    // ---- classifier ----
    classifier_k<<<1, 256, 0, stream>>>(pooled, wc, bc, out);
}

// Round 12
// 359.074 us; speedup vs baseline: 1.1958x; 1.0389x over previous
//
#include <hip/hip_runtime.h>
#include <hip/hip_bf16.h>

// GIN classifier. R11: fuse gather+BN+ReLU directly into the MLP kernel's LDS
// tile (wave-per-node 4-slot gather, proven in R4/R8, writes H rows straight
// to LDS; no H global round-trip). 12 -> 9 dispatches. gemm1_hist (R10, 107us)
// and CSR chain frozen.

#define N_NODES 100000
#define N_EDGES 800000
#define N_GRAPHS 128
#define NB_SCAN 391   // ceil(N_NODES/256)
#define LDP 136       // bf16 LDS row stride: 2-way bank alias only (free)
#define FLDP 68       // f32 row stride for pool staging
#define G1_BLOCKS 1563
#define HIST_BLOCKS 782   // 782*1024 >= 800000

typedef __bf16 bf16x8 __attribute__((ext_vector_type(8)));
typedef float f32x4 __attribute__((ext_vector_type(4)));
typedef unsigned short ushort_t;
typedef unsigned int uint_t;

static __device__ __forceinline__ ushort_t f2b(float f) {
    uint_t u = __builtin_bit_cast(uint_t, f);
    uint_t r = (u + 0x7fffu + ((u >> 16) & 1u)) >> 16;   // RNE
    return (ushort_t)r;
}
static __device__ __forceinline__ float b2f(ushort_t u) {
    return __builtin_bit_cast(float, (uint_t)u << 16);
}

// ---- weight transposes + zero ideg + zero pooled, one dispatch -------------
__global__ __launch_bounds__(256) void wt_all_k(
        const float* __restrict__ w1a, const float* __restrict__ w1b,
        const float* __restrict__ w2a, const float* __restrict__ w2b,
        const float* __restrict__ w3a, const float* __restrict__ w3b,
        ushort_t* __restrict__ o1a, ushort_t* __restrict__ o1b,
        ushort_t* __restrict__ o2a, ushort_t* __restrict__ o2b,
        ushort_t* __restrict__ o3a, ushort_t* __restrict__ o3b,
        int* __restrict__ ideg, float* __restrict__ pooled) {
    int t = blockIdx.x * 256 + threadIdx.x;
    if (t < 122880) {
        const float* W; ushort_t* O; int K, N, i;
        if      (t <  49152) { W = w1a; O = o1a; K = 384; N = 128; i = t; }
        else if (t <  65536) { W = w1b; O = o1b; K = 128; N = 128; i = t - 49152; }
        else if (t <  81920) { W = w2a; O = o2a; K = 128; N = 128; i = t - 65536; }
        else if (t <  98304) { W = w2b; O = o2b; K = 128; N = 128; i = t - 81920; }
        else if (t < 114688) { W = w3a; O = o3a; K = 128; N = 128; i = t - 98304; }
        else                 { W = w3b; O = o3b; K = 128; N = 64;  i = t - 114688; }
        int k = i / N, c = i % N;
        O[c * K + k] = f2b(W[i]);
    } else if (t < 222880) {
        ideg[t - 122880] = 0;
    } else if (t < 231072) {
        pooled[t - 222880] = 0.f;
    }
}

// ---- mega dispatch: gemm1 (R4 block structure) + CSR histogram -------------
__global__ __launch_bounds__(256) void gemm1_hist_k(const float* __restrict__ A,
                                                    const ushort_t* __restrict__ Wt,
                                                    ushort_t* __restrict__ C, int M,
                                                    const int* __restrict__ dst,
                                                    int* __restrict__ deg) {
    __shared__ ushort_t Al[64 * LDP];

    if (blockIdx.x >= G1_BLOCKS) {
        int b = blockIdx.x - G1_BLOCKS;
        int e0 = b * 1024 + threadIdx.x;
        #pragma unroll
        for (int p = 0; p < 4; ++p) {
            int e = e0 + p * 256;
            if (e < N_EDGES) atomicAdd(&deg[dst[e]], 1);
        }
        return;
    }

    constexpr int K = 384;
    const int tid  = threadIdx.x;
    const int lane = tid & 63;
    const int wid  = tid >> 6;
    const int wrow = wid >> 1;
    const int wcol = wid & 1;
    const int l15  = lane & 15;
    const int kg   = lane >> 4;
    const int row0 = blockIdx.x * 64;

    f32x4 acc[2][4];
    #pragma unroll
    for (int i = 0; i < 2; ++i)
        #pragma unroll
        for (int j = 0; j < 4; ++j)
            acc[i][j] = f32x4{0.f, 0.f, 0.f, 0.f};

    const int r  = tid >> 2;
    const int cc = (tid & 3) * 32;

    for (int k0 = 0; k0 < K; k0 += 128) {
        __syncthreads();
        {
            int gr = row0 + r;
            if (gr > M - 1) gr = M - 1;
            const float* pA = A + (size_t)gr * K + k0 + cc;
            float4 v[8];
            #pragma unroll
            for (int p = 0; p < 8; ++p)
                v[p] = *reinterpret_cast<const float4*>(pA + p * 4);
            uint_t u[16];
            #pragma unroll
            for (int p = 0; p < 8; ++p) {
                u[2 * p]     = (uint_t)f2b(v[p].x) | ((uint_t)f2b(v[p].y) << 16);
                u[2 * p + 1] = (uint_t)f2b(v[p].z) | ((uint_t)f2b(v[p].w) << 16);
            }
            uint4* dstp = reinterpret_cast<uint4*>(&Al[r * LDP + cc]);
            dstp[0] = make_uint4(u[0], u[1], u[2], u[3]);
            dstp[1] = make_uint4(u[4], u[5], u[6], u[7]);
            dstp[2] = make_uint4(u[8], u[9], u[10], u[11]);
            dstp[3] = make_uint4(u[12], u[13], u[14], u[15]);
        }
        __syncthreads();

        #pragma unroll
        for (int kk = 0; kk < 4; ++kk) {
            bf16x8 a0 = *reinterpret_cast<const bf16x8*>(&Al[(wrow * 32 + l15) * LDP + kk * 32 + kg * 8]);
            bf16x8 a1 = *reinterpret_cast<const bf16x8*>(&Al[(wrow * 32 + 16 + l15) * LDP + kk * 32 + kg * 8]);
            #pragma unroll
            for (int j = 0; j < 4; ++j) {
                int col = wcol * 64 + j * 16 + l15;
                bf16x8 b = *reinterpret_cast<const bf16x8*>(Wt + (size_t)col * K + k0 + kk * 32 + kg * 8);
                acc[0][j] = __builtin_amdgcn_mfma_f32_16x16x32_bf16(a0, b, acc[0][j], 0, 0, 0);
                acc[1][j] = __builtin_amdgcn_mfma_f32_16x16x32_bf16(a1, b, acc[1][j], 0, 0, 0);
            }
        }
    }

    __syncthreads();
    #pragma unroll
    for (int i = 0; i < 2; ++i)
        #pragma unroll
        for (int j = 0; j < 4; ++j) {
            int col = wcol * 64 + j * 16 + l15;
            #pragma unroll
            for (int q = 0; q < 4; ++q) {
                int row = wrow * 32 + i * 16 + kg * 4 + q;
                Al[row * LDP + col] = f2b(acc[i][j][q]);
            }
        }
    __syncthreads();
    #pragma unroll
    for (int p = 0; p < 4; ++p) {
        int idx = tid + p * 256;
        int rr = idx >> 4, c16 = idx & 15;
        int gr = row0 + rr;
        if (gr < M)
            *reinterpret_cast<uint4*>(C + (size_t)gr * 128 + c16 * 8) =
                *reinterpret_cast<const uint4*>(&Al[rr * LDP + c16 * 8]);
    }
}

// ---------------- CSR scan chain ----------------
__global__ __launch_bounds__(256) void scan1_k(const int* __restrict__ deg,
                                               int* __restrict__ tmp,
                                               int* __restrict__ bsum) {
    __shared__ int s[256];
    int i = blockIdx.x * 256 + threadIdx.x;
    int t = threadIdx.x;
    s[t] = (i < N_NODES) ? deg[i] : 0;
    __syncthreads();
    for (int off = 1; off < 256; off <<= 1) {
        int v = (t >= off) ? s[t - off] : 0;
        __syncthreads();
        s[t] += v;
        __syncthreads();
    }
    if (i < N_NODES) tmp[i] = s[t];
    if (t == 255) bsum[blockIdx.x] = s[255];
}

__global__ __launch_bounds__(256) void scan23_k(const int* __restrict__ tmp,
                                                const int* __restrict__ deg,
                                                const int* __restrict__ bsum,
                                                int* __restrict__ row_start) {
    __shared__ int sb[256];
    int t = threadIdx.x;
    int partial = 0;
    for (int i = t; i < (int)blockIdx.x; i += 256) partial += bsum[i];
    sb[t] = partial;
    __syncthreads();
    for (int off = 128; off > 0; off >>= 1) {
        if (t < off) sb[t] += sb[t + off];
        __syncthreads();
    }
    int boff = sb[0];
    int i = blockIdx.x * 256 + t;
    if (i < N_NODES) row_start[i] = tmp[i] - deg[i] + boff;
}

__global__ __launch_bounds__(256) void fill_k(const int* __restrict__ src,
                                              const int* __restrict__ dst,
                                              int* __restrict__ row_start,
                                              int* __restrict__ csr_src) {
    int e = blockIdx.x * 256 + threadIdx.x;
    if (e >= N_EDGES) return;
    int idx = atomicAdd(&row_start[dst[e]], 1);
    csr_src[idx] = src[e];
}

// ======== fused layer: gather+BN+ReLU -> LDS -> GEMM1(+b,relu) ->
//          [TAIL: pool]  or  [GEMM2 -> Yout] ================================
// Block = 64 nodes, 4 waves; wave w gathers nodes [w*16, w*16+16) with the
// proven wave-per-node 4-slot scheme, writing rows straight into Hl.
template<bool TAIL>
__global__ __launch_bounds__(256) void gather_mlp_k(
        const ushort_t* __restrict__ Yin,
        const int* __restrict__ csr, const int* __restrict__ rend,
        const int* __restrict__ deg,
        const float* __restrict__ epsp, const float* __restrict__ ba,
        const float* __restrict__ g, const float* __restrict__ be,
        const float* __restrict__ mm, const float* __restrict__ vv,
        const ushort_t* __restrict__ Wb, const float* __restrict__ bias1,
        const ushort_t* __restrict__ Wa2,
        ushort_t* __restrict__ Yout,
        const int* __restrict__ batch, float* __restrict__ pooled, int M) {
    constexpr int NJ1 = TAIL ? 2 : 4;       // N1 = 64 or 128
    __shared__ ushort_t Hl[64 * LDP];
    __shared__ ushort_t Xl[64 * LDP];       // f32 pool staging view for TAIL
    float* Fl = (float*)Xl;

    const int tid  = threadIdx.x;
    const int lane = tid & 63;
    const int wid  = tid >> 6;
    const int l15  = lane & 15;
    const int slot = lane >> 4;
    const int c0   = l15 * 8;
    const int row0 = blockIdx.x * 64;

    // ---- phase G: gather + BN + ReLU -> Hl (wave w owns rows w*16..w*16+15)
    {
        float ep = 1.0f + epsp[0];
        float sc[8], sh[8];
        #pragma unroll
        for (int jj = 0; jj < 8; ++jj) {
            int c = c0 + jj;
            float s = g[c] * rsqrtf(vv[c] + 1e-5f);
            sc[jj] = s;
            sh[jj] = (ba[c] - mm[c]) * s + be[c];
        }

        const int base = row0 + wid * 16;
        int cn = base; if (cn > M - 1) cn = M - 1;
        int end = rend[cn], d = deg[cn];
        int st = end - d;
        int nlim = (d > 64) ? 64 : d;
        int nb = (lane < nlim) ? csr[st + lane] : 0;

        for (int nl = 0; nl < 16; ++nl) {
            int node = base + nl; if (node > M - 1) node = M - 1;
            int nxt = base + nl + 1; if (nxt > M - 1) nxt = M - 1;
            int nend = 0, nd = 0;
            if (nl < 15) { nend = rend[nxt]; nd = deg[nxt]; }   // prefetch meta

            uint4 ow = *reinterpret_cast<const uint4*>(Yin + (size_t)node * 128 + c0);

            float acc[8] = {0.f, 0.f, 0.f, 0.f, 0.f, 0.f, 0.f, 0.f};
            for (int j0 = 0; j0 < nlim; j0 += 8) {
                int jA = j0 + slot;
                int jB = j0 + 4 + slot;
                int ia = __shfl(nb, jA & 63);
                int ib = __shfl(nb, jB & 63);
                uint4 wa = *reinterpret_cast<const uint4*>(Yin + (size_t)ia * 128 + c0);
                uint4 wb = *reinterpret_cast<const uint4*>(Yin + (size_t)ib * 128 + c0);
                float fa = (jA < nlim) ? 1.f : 0.f;
                float fb = (jB < nlim) ? 1.f : 0.f;
                uint_t ua[4] = {wa.x, wa.y, wa.z, wa.w};
                uint_t ub[4] = {wb.x, wb.y, wb.z, wb.w};
                #pragma unroll
                for (int p = 0; p < 4; ++p) {
                    acc[2 * p]     += fa * b2f((ushort_t)(ua[p] & 0xffff));
                    acc[2 * p + 1] += fa * b2f((ushort_t)(ua[p] >> 16));
                    acc[2 * p]     += fb * b2f((ushort_t)(ub[p] & 0xffff));
                    acc[2 * p + 1] += fb * b2f((ushort_t)(ub[p] >> 16));
                }
            }
            for (int j = st + 64; j < end; ++j) {
                if (slot == 0) {
                    int idx = csr[j];
                    uint4 w = *reinterpret_cast<const uint4*>(Yin + (size_t)idx * 128 + c0);
                    uint_t uw[4] = {w.x, w.y, w.z, w.w};
                    #pragma unroll
                    for (int p = 0; p < 4; ++p) {
                        acc[2 * p]     += b2f((ushort_t)(uw[p] & 0xffff));
                        acc[2 * p + 1] += b2f((ushort_t)(uw[p] >> 16));
                    }
                }
            }

            // prefetch next node's indices (overlaps reduce + BN + LDS write)
            int nst = nend - nd;
            int nnlim = (nd > 64) ? 64 : nd;
            int nb2 = 0;
            if (nl < 15 && lane < nnlim) nb2 = csr[nst + lane];

            #pragma unroll
            for (int jj = 0; jj < 8; ++jj) {
                acc[jj] += __shfl_xor(acc[jj], 16);
                acc[jj] += __shfl_xor(acc[jj], 32);
            }
            uint_t uo[4] = {ow.x, ow.y, ow.z, ow.w};
            ushort_t rr[8];
            #pragma unroll
            for (int p = 0; p < 4; ++p) {
                float o0 = b2f((ushort_t)(uo[p] & 0xffff));
                float o1 = b2f((ushort_t)(uo[p] >> 16));
                float t0 = sc[2 * p] * (ep * o0 + acc[2 * p]) + sh[2 * p];
                float t1 = sc[2 * p + 1] * (ep * o1 + acc[2 * p + 1]) + sh[2 * p + 1];
                rr[2 * p]     = f2b(fmaxf(t0, 0.f));
                rr[2 * p + 1] = f2b(fmaxf(t1, 0.f));
            }
            if (slot == 0) {
                uint4 packed;
                packed.x = (uint_t)rr[0] | ((uint_t)rr[1] << 16);
                packed.y = (uint_t)rr[2] | ((uint_t)rr[3] << 16);
                packed.z = (uint_t)rr[4] | ((uint_t)rr[5] << 16);
                packed.w = (uint_t)rr[6] | ((uint_t)rr[7] << 16);
                *reinterpret_cast<uint4*>(&Hl[(wid * 16 + nl) * LDP + c0]) = packed;
            }

            end = nend; d = nd; st = nst; nlim = nnlim; nb = nb2;
        }
    }
    __syncthreads();

    // ---- MLP phase (from mlp_k, minus global staging) ----
    const int wrow = wid >> 1;
    const int wcol = wid & 1;
    const int kg   = lane >> 4;

    f32x4 acc1[2][NJ1];
    #pragma unroll
    for (int i = 0; i < 2; ++i)
        #pragma unroll
        for (int j = 0; j < NJ1; ++j)
            acc1[i][j] = f32x4{0.f, 0.f, 0.f, 0.f};
    #pragma unroll
    for (int kk = 0; kk < 4; ++kk) {
        bf16x8 a0 = *reinterpret_cast<const bf16x8*>(&Hl[(wrow * 32 + l15) * LDP + kk * 32 + kg * 8]);
        bf16x8 a1 = *reinterpret_cast<const bf16x8*>(&Hl[(wrow * 32 + 16 + l15) * LDP + kk * 32 + kg * 8]);
        #pragma unroll
        for (int j = 0; j < NJ1; ++j) {
            int col = wcol * (16 * NJ1) + j * 16 + l15;
            bf16x8 b = *reinterpret_cast<const bf16x8*>(Wb + (size_t)col * 128 + kk * 32 + kg * 8);
            acc1[0][j] = __builtin_amdgcn_mfma_f32_16x16x32_bf16(a0, b, acc1[0][j], 0, 0, 0);
            acc1[1][j] = __builtin_amdgcn_mfma_f32_16x16x32_bf16(a1, b, acc1[1][j], 0, 0, 0);
        }
    }

    if constexpr (TAIL) {
        #pragma unroll
        for (int i = 0; i < 2; ++i)
            #pragma unroll
            for (int j = 0; j < NJ1; ++j) {
                int col = wcol * 32 + j * 16 + l15;
                float bi = bias1[col];
                #pragma unroll
                for (int q = 0; q < 4; ++q) {
                    int row = wrow * 32 + i * 16 + kg * 4 + q;
                    Fl[row * FLDP + col] = fmaxf(acc1[i][j][q] + bi, 0.f);
                }
            }
        __syncthreads();
        int col = tid & 63;
        int qq  = tid >> 6;
        float a = 0.f;
        int cur = -1;
        for (int rr2 = 0; rr2 < 16; ++rr2) {
            int r = qq * 16 + rr2;
            int gr = row0 + r;
            if (gr >= M) break;
            int b = batch[gr];
            if (b != cur) {
                if (cur >= 0) atomicAdd(&pooled[cur * 64 + col], a);
                a = 0.f;
                cur = b;
            }
            a += Fl[r * FLDP + col];
        }
        if (cur >= 0) atomicAdd(&pooled[cur * 64 + col], a);
    } else {
        #pragma unroll
        for (int i = 0; i < 2; ++i)
            #pragma unroll
            for (int j = 0; j < NJ1; ++j) {
                int col = wcol * 64 + j * 16 + l15;
                float bi = bias1[col];
                #pragma unroll
                for (int q = 0; q < 4; ++q) {
                    int row = wrow * 32 + i * 16 + kg * 4 + q;
                    Xl[row * LDP + col] = f2b(fmaxf(acc1[i][j][q] + bi, 0.f));
                }
            }
        __syncthreads();

        f32x4 acc2[2][4];
        #pragma unroll
        for (int i = 0; i < 2; ++i)
            #pragma unroll
            for (int j = 0; j < 4; ++j)
                acc2[i][j] = f32x4{0.f, 0.f, 0.f, 0.f};
        #pragma unroll
        for (int kk = 0; kk < 4; ++kk) {
            bf16x8 a0 = *reinterpret_cast<const bf16x8*>(&Xl[(wrow * 32 + l15) * LDP + kk * 32 + kg * 8]);
            bf16x8 a1 = *reinterpret_cast<const bf16x8*>(&Xl[(wrow * 32 + 16 + l15) * LDP + kk * 32 + kg * 8]);
            #pragma unroll
            for (int j = 0; j < 4; ++j) {
                int col = wcol * 64 + j * 16 + l15;
                bf16x8 b = *reinterpret_cast<const bf16x8*>(Wa2 + (size_t)col * 128 + kk * 32 + kg * 8);
                acc2[0][j] = __builtin_amdgcn_mfma_f32_16x16x32_bf16(a0, b, acc2[0][j], 0, 0, 0);
                acc2[1][j] = __builtin_amdgcn_mfma_f32_16x16x32_bf16(a1, b, acc2[1][j], 0, 0, 0);
            }
        }
        __syncthreads();   // Hl reads (GEMM1) done; reuse Hl for output staging
        #pragma unroll
        for (int i = 0; i < 2; ++i)
            #pragma unroll
            for (int j = 0; j < 4; ++j) {
                int col = wcol * 64 + j * 16 + l15;
                #pragma unroll
                for (int q = 0; q < 4; ++q) {
                    int row = wrow * 32 + i * 16 + kg * 4 + q;
                    Hl[row * LDP + col] = f2b(acc2[i][j][q]);
                }
            }
        __syncthreads();
        #pragma unroll
        for (int p = 0; p < 4; ++p) {
            int idx = tid + p * 256;
            int r = idx >> 4, c16 = idx & 15;
            int gr = row0 + r;
            if (gr < M)
                *reinterpret_cast<uint4*>(Yout + (size_t)gr * 128 + c16 * 8) =
                    *reinterpret_cast<const uint4*>(&Hl[r * LDP + c16 * 8]);
        }
    }
}

// ---------------- classifier ----------------
__global__ __launch_bounds__(256) void classifier_k(const float* __restrict__ pooled,
                                                    const float* __restrict__ wc,
                                                    const float* __restrict__ bc,
                                                    float* __restrict__ out) {
    int t = threadIdx.x;
    int gidx = t >> 1, c = t & 1;
    float s = bc[c];
    #pragma unroll
    for (int k = 0; k < 64; ++k)
        s += pooled[gidx * 64 + k] * wc[k * 2 + c];
    out[gidx * 2 + c] = s;
}

extern "C" void kernel_launch(void* const* d_in, const int* in_sizes, int n_in,
                              void* d_out, int out_size, void* d_ws, size_t ws_size,
                              hipStream_t stream) {
    const float* x     = (const float*)d_in[0];
    const int*   ei    = (const int*)d_in[1];
    const int*   src   = ei;
    const int*   dst   = ei + N_EDGES;
    const int*   batch = (const int*)d_in[2];
    const float* eps1 = (const float*)d_in[3];
    const float* w1a  = (const float*)d_in[4];
    const float* b1a  = (const float*)d_in[5];
    const float* g1   = (const float*)d_in[6];
    const float* be1  = (const float*)d_in[7];
    const float* m1   = (const float*)d_in[8];
    const float* v1   = (const float*)d_in[9];
    const float* w1b  = (const float*)d_in[10];
    const float* b1b  = (const float*)d_in[11];
    const float* eps2 = (const float*)d_in[12];
    const float* w2a  = (const float*)d_in[13];
    const float* b2a  = (const float*)d_in[14];
    const float* g2   = (const float*)d_in[15];
    const float* be2  = (const float*)d_in[16];
    const float* m2   = (const float*)d_in[17];
    const float* v2   = (const float*)d_in[18];
    const float* w2b  = (const float*)d_in[19];
    const float* b2b  = (const float*)d_in[20];
    const float* eps3 = (const float*)d_in[21];
    const float* w3a  = (const float*)d_in[22];
    const float* b3a  = (const float*)d_in[23];
    const float* g3   = (const float*)d_in[24];
    const float* be3  = (const float*)d_in[25];
    const float* m3   = (const float*)d_in[26];
    const float* v3   = (const float*)d_in[27];
    const float* w3b  = (const float*)d_in[28];
    const float* b3b  = (const float*)d_in[29];
    const float* wc   = (const float*)d_in[30];
    const float* bc   = (const float*)d_in[31];
    float* out = (float*)d_out;

    // workspace layout
    ushort_t* Y = (ushort_t*)d_ws;             // [100000,128] bf16
    ushort_t* H = Y + 12800000;                // [100000,128] bf16 (ping-pong)
    ushort_t* wt1a = H + 12800000;             // 384*128
    ushort_t* wt1b = wt1a + 49152;             // 128*128
    ushort_t* wt2a = wt1b + 16384;
    ushort_t* wt2b = wt2a + 16384;
    ushort_t* wt3a = wt2b + 16384;
    ushort_t* wt3b = wt3a + 16384;             // 64*128
    float* pooled = (float*)(wt3b + 8192);     // [128,64]
    int* ideg = (int*)(pooled + 8192);         // [100000]
    int* irow = ideg + N_NODES;
    int* itmp = irow + N_NODES;
    int* icsr = itmp + N_NODES;                // [800000]
    int* ibsum = icsr + N_EDGES;               // [391]

    const int M = N_NODES;
    const int gGemm = (M + 63) / 64;           // 1563
    const int gEdge = (N_EDGES + 255) / 256;   // 3125
    const int gNode = NB_SCAN;                 // 391

    // ---- 1: weight transposes + zero ideg + zero pooled ----
    wt_all_k<<<903, 256, 0, stream>>>(w1a, w1b, w2a, w2b, w3a, w3b,
                                      wt1a, wt1b, wt2a, wt2b, wt3a, wt3b,
                                      ideg, pooled);

    // ---- 2: gemm1 + histogram ----
    gemm1_hist_k<<<G1_BLOCKS + HIST_BLOCKS, 256, 0, stream>>>(x, wt1a, Y, M, dst, ideg);

    // ---- 3-5: scan chain + fill ----
    scan1_k<<<gNode, 256, 0, stream>>>(ideg, itmp, ibsum);
    scan23_k<<<gNode, 256, 0, stream>>>(itmp, ideg, ibsum, irow);
    fill_k<<<gEdge, 256, 0, stream>>>(src, dst, irow, icsr);

    // ---- 6-8: fused layers ----
    gather_mlp_k<false><<<gGemm, 256, 0, stream>>>(
        Y, icsr, irow, ideg, eps1, b1a, g1, be1, m1, v1,
        wt1b, b1b, wt2a, H, nullptr, nullptr, M);
    gather_mlp_k<false><<<gGemm, 256, 0, stream>>>(
        H, icsr, irow, ideg, eps2, b2a, g2, be2, m2, v2,
        wt2b, b2b, wt3a, Y, nullptr, nullptr, M);
    gather_mlp_k<true><<<gGemm, 256, 0, stream>>>(
        Y, icsr, irow, ideg, eps3, b3a, g3, be3, m3, v3,
        wt3b, b3b, nullptr, nullptr, batch, pooled, M);

    // ---- 9: classifier ----
    classifier_k<<<1, 256, 0, stream>>>(pooled, wc, bc, out);
}

// Round 13
// 353.673 us; speedup vs baseline: 1.2140x; 1.0153x over previous
//
#include <hip/hip_runtime.h>
#include <hip/hip_bf16.h>

// GIN classifier. R12: gemm1 rebuilt with async global_load_lds (width16)
// double-buffered 2-phase pipeline; A staged as fp32 with XOR-swizzled source
// (both-sides swizzle, LDS linear), bf16 convert at fragment-read time.
// Everything else frozen from R11.

#define N_NODES 100000
#define N_EDGES 800000
#define N_GRAPHS 128
#define NB_SCAN 391   // ceil(N_NODES/256)
#define LDP 136       // bf16 LDS row stride: 2-way bank alias only (free)
#define FLDP 68       // f32 row stride for pool staging
#define G1_BLOCKS 1563
#define HIST_BLOCKS 782   // 782*1024 >= 800000

typedef __bf16 bf16x8 __attribute__((ext_vector_type(8)));
typedef float f32x4 __attribute__((ext_vector_type(4)));
typedef unsigned short ushort_t;
typedef unsigned int uint_t;

static __device__ __forceinline__ ushort_t f2b(float f) {
    uint_t u = __builtin_bit_cast(uint_t, f);
    uint_t r = (u + 0x7fffu + ((u >> 16) & 1u)) >> 16;   // RNE
    return (ushort_t)r;
}
static __device__ __forceinline__ float b2f(ushort_t u) {
    return __builtin_bit_cast(float, (uint_t)u << 16);
}

static __device__ __forceinline__ void gload_lds16(const float* gp, float* lp) {
    __builtin_amdgcn_global_load_lds(
        (const __attribute__((address_space(1))) void*)gp,
        (__attribute__((address_space(3))) void*)lp, 16, 0, 0);
}

// ---- weight transposes + zero ideg + zero pooled, one dispatch -------------
__global__ __launch_bounds__(256) void wt_all_k(
        const float* __restrict__ w1a, const float* __restrict__ w1b,
        const float* __restrict__ w2a, const float* __restrict__ w2b,
        const float* __restrict__ w3a, const float* __restrict__ w3b,
        ushort_t* __restrict__ o1a, ushort_t* __restrict__ o1b,
        ushort_t* __restrict__ o2a, ushort_t* __restrict__ o2b,
        ushort_t* __restrict__ o3a, ushort_t* __restrict__ o3b,
        int* __restrict__ ideg, float* __restrict__ pooled) {
    int t = blockIdx.x * 256 + threadIdx.x;
    if (t < 122880) {
        const float* W; ushort_t* O; int K, N, i;
        if      (t <  49152) { W = w1a; O = o1a; K = 384; N = 128; i = t; }
        else if (t <  65536) { W = w1b; O = o1b; K = 128; N = 128; i = t - 49152; }
        else if (t <  81920) { W = w2a; O = o2a; K = 128; N = 128; i = t - 65536; }
        else if (t <  98304) { W = w2b; O = o2b; K = 128; N = 128; i = t - 81920; }
        else if (t < 114688) { W = w3a; O = o3a; K = 128; N = 128; i = t - 98304; }
        else                 { W = w3b; O = o3b; K = 128; N = 64;  i = t - 114688; }
        int k = i / N, c = i % N;
        O[c * K + k] = f2b(W[i]);
    } else if (t < 222880) {
        ideg[t - 122880] = 0;
    } else if (t < 231072) {
        pooled[t - 222880] = 0.f;
    }
}

// ---- mega dispatch: gemm1 (async-LDS double-buffered) + CSR histogram ------
// gemm1: C[M,128] = bf16(A fp32 [M,384]) @ Wt. BM=64, BK=64, 6 k-steps.
// A staged fp32 via global_load_lds w/ source-XOR swizzle; 2-phase dbuf.
__global__ __launch_bounds__(256) void gemm1_hist_k(const float* __restrict__ A,
                                                    const ushort_t* __restrict__ Wt,
                                                    ushort_t* __restrict__ C, int M,
                                                    const int* __restrict__ dst,
                                                    int* __restrict__ deg) {
    __shared__ float Af[2][64 * 64];          // 2 x 16 KB

    if (blockIdx.x >= G1_BLOCKS) {
        int b = blockIdx.x - G1_BLOCKS;
        int e0 = b * 1024 + threadIdx.x;
        #pragma unroll
        for (int p = 0; p < 4; ++p) {
            int e = e0 + p * 256;
            if (e < N_EDGES) atomicAdd(&deg[dst[e]], 1);
        }
        return;
    }

    constexpr int K = 384;
    const int tid  = threadIdx.x;
    const int lane = tid & 63;
    const int wid  = tid >> 6;
    const int wrow = wid >> 1;
    const int wcol = wid & 1;
    const int l15  = lane & 15;
    const int kg   = lane >> 4;
    const int row0 = blockIdx.x * 64;

    // staging geometry (per thread, per load p): LDS 16B-unit U = p*256+wid*64+lane
    // row R = U/16 = p*16 + wid*4 + (lane>>4); col unit c = lane&15.
    // source pre-swizzled: global unit cs = c ^ (R&7); LDS stays linear.
    const int Rb = wid * 4 + (lane >> 4);     // R for p=0
    int grs[4]; int css[4];
    #pragma unroll
    for (int p = 0; p < 4; ++p) {
        int R = p * 16 + Rb;
        int gr = row0 + R; if (gr > M - 1) gr = M - 1;
        grs[p] = gr;
        css[p] = (lane & 15) ^ (R & 7);
    }

    f32x4 acc[2][4];
    #pragma unroll
    for (int i = 0; i < 2; ++i)
        #pragma unroll
        for (int j = 0; j < 4; ++j)
            acc[i][j] = f32x4{0.f, 0.f, 0.f, 0.f};

    // prologue: stage tile 0 into buf 0
    #pragma unroll
    for (int p = 0; p < 4; ++p)
        gload_lds16(A + (size_t)grs[p] * K + 0 + css[p] * 4,
                    &Af[0][p * 1024 + wid * 256]);
    __syncthreads();

    int cur = 0;
    const int rA0 = wrow * 32 + l15;          // fragment rows
    const int rA1 = wrow * 32 + 16 + l15;
    const int s0 = rA0 & 7, s1 = rA1 & 7;

    #pragma unroll
    for (int t = 0; t < 6; ++t) {
        if (t < 5) {
            int k0n = (t + 1) * 64;
            #pragma unroll
            for (int p = 0; p < 4; ++p)
                gload_lds16(A + (size_t)grs[p] * K + k0n + css[p] * 4,
                            &Af[cur ^ 1][p * 1024 + wid * 256]);
        }
        const float* B0 = &Af[cur][rA0 * 64];
        const float* B1 = &Af[cur][rA1 * 64];
        #pragma unroll
        for (int kk = 0; kk < 2; ++kk) {
            int u0 = kk * 8 + kg * 2;
            float4 lo0 = *reinterpret_cast<const float4*>(B0 + ((u0) ^ s0) * 4);
            float4 hi0 = *reinterpret_cast<const float4*>(B0 + ((u0 + 1) ^ s0) * 4);
            float4 lo1 = *reinterpret_cast<const float4*>(B1 + ((u0) ^ s1) * 4);
            float4 hi1 = *reinterpret_cast<const float4*>(B1 + ((u0 + 1) ^ s1) * 4);
            bf16x8 a0, a1;
            a0[0] = (__bf16)lo0.x; a0[1] = (__bf16)lo0.y; a0[2] = (__bf16)lo0.z; a0[3] = (__bf16)lo0.w;
            a0[4] = (__bf16)hi0.x; a0[5] = (__bf16)hi0.y; a0[6] = (__bf16)hi0.z; a0[7] = (__bf16)hi0.w;
            a1[0] = (__bf16)lo1.x; a1[1] = (__bf16)lo1.y; a1[2] = (__bf16)lo1.z; a1[3] = (__bf16)lo1.w;
            a1[4] = (__bf16)hi1.x; a1[5] = (__bf16)hi1.y; a1[6] = (__bf16)hi1.z; a1[7] = (__bf16)hi1.w;
            #pragma unroll
            for (int j = 0; j < 4; ++j) {
                int col = wcol * 64 + j * 16 + l15;
                bf16x8 b = *reinterpret_cast<const bf16x8*>(Wt + (size_t)col * K + t * 64 + kk * 32 + kg * 8);
                acc[0][j] = __builtin_amdgcn_mfma_f32_16x16x32_bf16(a0, b, acc[0][j], 0, 0, 0);
                acc[1][j] = __builtin_amdgcn_mfma_f32_16x16x32_bf16(a1, b, acc[1][j], 0, 0, 0);
            }
        }
        __syncthreads();          // drains vmcnt (next tile landed) + read fence
        cur ^= 1;
    }

    // epilogue: stage bf16 rows in LDS (reuse Af), full-line coalesced store
    ushort_t* Es = (ushort_t*)&Af[0][0];
    #pragma unroll
    for (int i = 0; i < 2; ++i)
        #pragma unroll
        for (int j = 0; j < 4; ++j) {
            int col = wcol * 64 + j * 16 + l15;
            #pragma unroll
            for (int q = 0; q < 4; ++q) {
                int row = wrow * 32 + i * 16 + kg * 4 + q;
                Es[row * LDP + col] = f2b(acc[i][j][q]);
            }
        }
    __syncthreads();
    #pragma unroll
    for (int p = 0; p < 4; ++p) {
        int idx = tid + p * 256;
        int rr = idx >> 4, c16 = idx & 15;
        int gr = row0 + rr;
        if (gr < M)
            *reinterpret_cast<uint4*>(C + (size_t)gr * 128 + c16 * 8) =
                *reinterpret_cast<const uint4*>(&Es[rr * LDP + c16 * 8]);
    }
}

// ---------------- CSR scan chain ----------------
__global__ __launch_bounds__(256) void scan1_k(const int* __restrict__ deg,
                                               int* __restrict__ tmp,
                                               int* __restrict__ bsum) {
    __shared__ int s[256];
    int i = blockIdx.x * 256 + threadIdx.x;
    int t = threadIdx.x;
    s[t] = (i < N_NODES) ? deg[i] : 0;
    __syncthreads();
    for (int off = 1; off < 256; off <<= 1) {
        int v = (t >= off) ? s[t - off] : 0;
        __syncthreads();
        s[t] += v;
        __syncthreads();
    }
    if (i < N_NODES) tmp[i] = s[t];
    if (t == 255) bsum[blockIdx.x] = s[255];
}

__global__ __launch_bounds__(256) void scan23_k(const int* __restrict__ tmp,
                                                const int* __restrict__ deg,
                                                const int* __restrict__ bsum,
                                                int* __restrict__ row_start) {
    __shared__ int sb[256];
    int t = threadIdx.x;
    int partial = 0;
    for (int i = t; i < (int)blockIdx.x; i += 256) partial += bsum[i];
    sb[t] = partial;
    __syncthreads();
    for (int off = 128; off > 0; off >>= 1) {
        if (t < off) sb[t] += sb[t + off];
        __syncthreads();
    }
    int boff = sb[0];
    int i = blockIdx.x * 256 + t;
    if (i < N_NODES) row_start[i] = tmp[i] - deg[i] + boff;
}

__global__ __launch_bounds__(256) void fill_k(const int* __restrict__ src,
                                              const int* __restrict__ dst,
                                              int* __restrict__ row_start,
                                              int* __restrict__ csr_src) {
    int e = blockIdx.x * 256 + threadIdx.x;
    if (e >= N_EDGES) return;
    int idx = atomicAdd(&row_start[dst[e]], 1);
    csr_src[idx] = src[e];
}

// ======== fused layer: gather+BN+ReLU -> LDS -> GEMM1(+b,relu) ->
//          [TAIL: pool]  or  [GEMM2 -> Yout] ================================
template<bool TAIL>
__global__ __launch_bounds__(256) void gather_mlp_k(
        const ushort_t* __restrict__ Yin,
        const int* __restrict__ csr, const int* __restrict__ rend,
        const int* __restrict__ deg,
        const float* __restrict__ epsp, const float* __restrict__ ba,
        const float* __restrict__ g, const float* __restrict__ be,
        const float* __restrict__ mm, const float* __restrict__ vv,
        const ushort_t* __restrict__ Wb, const float* __restrict__ bias1,
        const ushort_t* __restrict__ Wa2,
        ushort_t* __restrict__ Yout,
        const int* __restrict__ batch, float* __restrict__ pooled, int M) {
    constexpr int NJ1 = TAIL ? 2 : 4;       // N1 = 64 or 128
    __shared__ ushort_t Hl[64 * LDP];
    __shared__ ushort_t Xl[64 * LDP];       // f32 pool staging view for TAIL
    float* Fl = (float*)Xl;

    const int tid  = threadIdx.x;
    const int lane = tid & 63;
    const int wid  = tid >> 6;
    const int l15  = lane & 15;
    const int slot = lane >> 4;
    const int c0   = l15 * 8;
    const int row0 = blockIdx.x * 64;

    // ---- phase G: gather + BN + ReLU -> Hl (wave w owns rows w*16..w*16+15)
    {
        float ep = 1.0f + epsp[0];
        float sc[8], sh[8];
        #pragma unroll
        for (int jj = 0; jj < 8; ++jj) {
            int c = c0 + jj;
            float s = g[c] * rsqrtf(vv[c] + 1e-5f);
            sc[jj] = s;
            sh[jj] = (ba[c] - mm[c]) * s + be[c];
        }

        const int base = row0 + wid * 16;
        int cn = base; if (cn > M - 1) cn = M - 1;
        int end = rend[cn], d = deg[cn];
        int st = end - d;
        int nlim = (d > 64) ? 64 : d;
        int nb = (lane < nlim) ? csr[st + lane] : 0;

        for (int nl = 0; nl < 16; ++nl) {
            int node = base + nl; if (node > M - 1) node = M - 1;
            int nxt = base + nl + 1; if (nxt > M - 1) nxt = M - 1;
            int nend = 0, nd = 0;
            if (nl < 15) { nend = rend[nxt]; nd = deg[nxt]; }   // prefetch meta

            uint4 ow = *reinterpret_cast<const uint4*>(Yin + (size_t)node * 128 + c0);

            float acc[8] = {0.f, 0.f, 0.f, 0.f, 0.f, 0.f, 0.f, 0.f};
            for (int j0 = 0; j0 < nlim; j0 += 8) {
                int jA = j0 + slot;
                int jB = j0 + 4 + slot;
                int ia = __shfl(nb, jA & 63);
                int ib = __shfl(nb, jB & 63);
                uint4 wa = *reinterpret_cast<const uint4*>(Yin + (size_t)ia * 128 + c0);
                uint4 wb = *reinterpret_cast<const uint4*>(Yin + (size_t)ib * 128 + c0);
                float fa = (jA < nlim) ? 1.f : 0.f;
                float fb = (jB < nlim) ? 1.f : 0.f;
                uint_t ua[4] = {wa.x, wa.y, wa.z, wa.w};
                uint_t ub[4] = {wb.x, wb.y, wb.z, wb.w};
                #pragma unroll
                for (int p = 0; p < 4; ++p) {
                    acc[2 * p]     += fa * b2f((ushort_t)(ua[p] & 0xffff));
                    acc[2 * p + 1] += fa * b2f((ushort_t)(ua[p] >> 16));
                    acc[2 * p]     += fb * b2f((ushort_t)(ub[p] & 0xffff));
                    acc[2 * p + 1] += fb * b2f((ushort_t)(ub[p] >> 16));
                }
            }
            for (int j = st + 64; j < end; ++j) {
                if (slot == 0) {
                    int idx = csr[j];
                    uint4 w = *reinterpret_cast<const uint4*>(Yin + (size_t)idx * 128 + c0);
                    uint_t uw[4] = {w.x, w.y, w.z, w.w};
                    #pragma unroll
                    for (int p = 0; p < 4; ++p) {
                        acc[2 * p]     += b2f((ushort_t)(uw[p] & 0xffff));
                        acc[2 * p + 1] += b2f((ushort_t)(uw[p] >> 16));
                    }
                }
            }

            // prefetch next node's indices (overlaps reduce + BN + LDS write)
            int nst = nend - nd;
            int nnlim = (nd > 64) ? 64 : nd;
            int nb2 = 0;
            if (nl < 15 && lane < nnlim) nb2 = csr[nst + lane];

            #pragma unroll
            for (int jj = 0; jj < 8; ++jj) {
                acc[jj] += __shfl_xor(acc[jj], 16);
                acc[jj] += __shfl_xor(acc[jj], 32);
            }
            uint_t uo[4] = {ow.x, ow.y, ow.z, ow.w};
            ushort_t rr[8];
            #pragma unroll
            for (int p = 0; p < 4; ++p) {
                float o0 = b2f((ushort_t)(uo[p] & 0xffff));
                float o1 = b2f((ushort_t)(uo[p] >> 16));
                float t0 = sc[2 * p] * (ep * o0 + acc[2 * p]) + sh[2 * p];
                float t1 = sc[2 * p + 1] * (ep * o1 + acc[2 * p + 1]) + sh[2 * p + 1];
                rr[2 * p]     = f2b(fmaxf(t0, 0.f));
                rr[2 * p + 1] = f2b(fmaxf(t1, 0.f));
            }
            if (slot == 0) {
                uint4 packed;
                packed.x = (uint_t)rr[0] | ((uint_t)rr[1] << 16);
                packed.y = (uint_t)rr[2] | ((uint_t)rr[3] << 16);
                packed.z = (uint_t)rr[4] | ((uint_t)rr[5] << 16);
                packed.w = (uint_t)rr[6] | ((uint_t)rr[7] << 16);
                *reinterpret_cast<uint4*>(&Hl[(wid * 16 + nl) * LDP + c0]) = packed;
            }

            end = nend; d = nd; st = nst; nlim = nnlim; nb = nb2;
        }
    }
    __syncthreads();

    // ---- MLP phase ----
    const int wrow = wid >> 1;
    const int wcol = wid & 1;
    const int kg   = lane >> 4;

    f32x4 acc1[2][NJ1];
    #pragma unroll
    for (int i = 0; i < 2; ++i)
        #pragma unroll
        for (int j = 0; j < NJ1; ++j)
            acc1[i][j] = f32x4{0.f, 0.f, 0.f, 0.f};
    #pragma unroll
    for (int kk = 0; kk < 4; ++kk) {
        bf16x8 a0 = *reinterpret_cast<const bf16x8*>(&Hl[(wrow * 32 + l15) * LDP + kk * 32 + kg * 8]);
        bf16x8 a1 = *reinterpret_cast<const bf16x8*>(&Hl[(wrow * 32 + 16 + l15) * LDP + kk * 32 + kg * 8]);
        #pragma unroll
        for (int j = 0; j < NJ1; ++j) {
            int col = wcol * (16 * NJ1) + j * 16 + l15;
            bf16x8 b = *reinterpret_cast<const bf16x8*>(Wb + (size_t)col * 128 + kk * 32 + kg * 8);
            acc1[0][j] = __builtin_amdgcn_mfma_f32_16x16x32_bf16(a0, b, acc1[0][j], 0, 0, 0);
            acc1[1][j] = __builtin_amdgcn_mfma_f32_16x16x32_bf16(a1, b, acc1[1][j], 0, 0, 0);
        }
    }

    if constexpr (TAIL) {
        #pragma unroll
        for (int i = 0; i < 2; ++i)
            #pragma unroll
            for (int j = 0; j < NJ1; ++j) {
                int col = wcol * 32 + j * 16 + l15;
                float bi = bias1[col];
                #pragma unroll
                for (int q = 0; q < 4; ++q) {
                    int row = wrow * 32 + i * 16 + kg * 4 + q;
                    Fl[row * FLDP + col] = fmaxf(acc1[i][j][q] + bi, 0.f);
                }
            }
        __syncthreads();
        int col = tid & 63;
        int qq  = tid >> 6;
        float a = 0.f;
        int cur = -1;
        for (int rr2 = 0; rr2 < 16; ++rr2) {
            int r = qq * 16 + rr2;
            int gr = row0 + r;
            if (gr >= M) break;
            int b = batch[gr];
            if (b != cur) {
                if (cur >= 0) atomicAdd(&pooled[cur * 64 + col], a);
                a = 0.f;
                cur = b;
            }
            a += Fl[r * FLDP + col];
        }
        if (cur >= 0) atomicAdd(&pooled[cur * 64 + col], a);
    } else {
        #pragma unroll
        for (int i = 0; i < 2; ++i)
            #pragma unroll
            for (int j = 0; j < NJ1; ++j) {
                int col = wcol * 64 + j * 16 + l15;
                float bi = bias1[col];
                #pragma unroll
                for (int q = 0; q < 4; ++q) {
                    int row = wrow * 32 + i * 16 + kg * 4 + q;
                    Xl[row * LDP + col] = f2b(fmaxf(acc1[i][j][q] + bi, 0.f));
                }
            }
        __syncthreads();

        f32x4 acc2[2][4];
        #pragma unroll
        for (int i = 0; i < 2; ++i)
            #pragma unroll
            for (int j = 0; j < 4; ++j)
                acc2[i][j] = f32x4{0.f, 0.f, 0.f, 0.f};
        #pragma unroll
        for (int kk = 0; kk < 4; ++kk) {
            bf16x8 a0 = *reinterpret_cast<const bf16x8*>(&Xl[(wrow * 32 + l15) * LDP + kk * 32 + kg * 8]);
            bf16x8 a1 = *reinterpret_cast<const bf16x8*>(&Xl[(wrow * 32 + 16 + l15) * LDP + kk * 32 + kg * 8]);
            #pragma unroll
            for (int j = 0; j < 4; ++j) {
                int col = wcol * 64 + j * 16 + l15;
                bf16x8 b = *reinterpret_cast<const bf16x8*>(Wa2 + (size_t)col * 128 + kk * 32 + kg * 8);
                acc2[0][j] = __builtin_amdgcn_mfma_f32_16x16x32_bf16(a0, b, acc2[0][j], 0, 0, 0);
                acc2[1][j] = __builtin_amdgcn_mfma_f32_16x16x32_bf16(a1, b, acc2[1][j], 0, 0, 0);
            }
        }
        __syncthreads();   // Hl reads (GEMM1) done; reuse Hl for output staging
        #pragma unroll
        for (int i = 0; i < 2; ++i)
            #pragma unroll
            for (int j = 0; j < 4; ++j) {
                int col = wcol * 64 + j * 16 + l15;
                #pragma unroll
                for (int q = 0; q < 4; ++q) {
                    int row = wrow * 32 + i * 16 + kg * 4 + q;
                    Hl[row * LDP + col] = f2b(acc2[i][j][q]);
                }
            }
        __syncthreads();
        #pragma unroll
        for (int p = 0; p < 4; ++p) {
            int idx = tid + p * 256;
            int r = idx >> 4, c16 = idx & 15;
            int gr = row0 + r;
            if (gr < M)
                *reinterpret_cast<uint4*>(Yout + (size_t)gr * 128 + c16 * 8) =
                    *reinterpret_cast<const uint4*>(&Hl[r * LDP + c16 * 8]);
        }
    }
}

// ---------------- classifier ----------------
__global__ __launch_bounds__(256) void classifier_k(const float* __restrict__ pooled,
                                                    const float* __restrict__ wc,
                                                    const float* __restrict__ bc,
                                                    float* __restrict__ out) {
    int t = threadIdx.x;
    int gidx = t >> 1, c = t & 1;
    float s = bc[c];
    #pragma unroll
    for (int k = 0; k < 64; ++k)
        s += pooled[gidx * 64 + k] * wc[k * 2 + c];
    out[gidx * 2 + c] = s;
}

extern "C" void kernel_launch(void* const* d_in, const int* in_sizes, int n_in,
                              void* d_out, int out_size, void* d_ws, size_t ws_size,
                              hipStream_t stream) {
    const float* x     = (const float*)d_in[0];
    const int*   ei    = (const int*)d_in[1];
    const int*   src   = ei;
    const int*   dst   = ei + N_EDGES;
    const int*   batch = (const int*)d_in[2];
    const float* eps1 = (const float*)d_in[3];
    const float* w1a  = (const float*)d_in[4];
    const float* b1a  = (const float*)d_in[5];
    const float* g1   = (const float*)d_in[6];
    const float* be1  = (const float*)d_in[7];
    const float* m1   = (const float*)d_in[8];
    const float* v1   = (const float*)d_in[9];
    const float* w1b  = (const float*)d_in[10];
    const float* b1b  = (const float*)d_in[11];
    const float* eps2 = (const float*)d_in[12];
    const float* w2a  = (const float*)d_in[13];
    const float* b2a  = (const float*)d_in[14];
    const float* g2   = (const float*)d_in[15];
    const float* be2  = (const float*)d_in[16];
    const float* m2   = (const float*)d_in[17];
    const float* v2   = (const float*)d_in[18];
    const float* w2b  = (const float*)d_in[19];
    const float* b2b  = (const float*)d_in[20];
    const float* eps3 = (const float*)d_in[21];
    const float* w3a  = (const float*)d_in[22];
    const float* b3a  = (const float*)d_in[23];
    const float* g3   = (const float*)d_in[24];
    const float* be3  = (const float*)d_in[25];
    const float* m3   = (const float*)d_in[26];
    const float* v3   = (const float*)d_in[27];
    const float* w3b  = (const float*)d_in[28];
    const float* b3b  = (const float*)d_in[29];
    const float* wc   = (const float*)d_in[30];
    const float* bc   = (const float*)d_in[31];
    float* out = (float*)d_out;

    // workspace layout
    ushort_t* Y = (ushort_t*)d_ws;             // [100000,128] bf16
    ushort_t* H = Y + 12800000;                // [100000,128] bf16 (ping-pong)
    ushort_t* wt1a = H + 12800000;             // 384*128
    ushort_t* wt1b = wt1a + 49152;             // 128*128
    ushort_t* wt2a = wt1b + 16384;
    ushort_t* wt2b = wt2a + 16384;
    ushort_t* wt3a = wt2b + 16384;
    ushort_t* wt3b = wt3a + 16384;             // 64*128
    float* pooled = (float*)(wt3b + 8192);     // [128,64]
    int* ideg = (int*)(pooled + 8192);         // [100000]
    int* irow = ideg + N_NODES;
    int* itmp = irow + N_NODES;
    int* icsr = itmp + N_NODES;                // [800000]
    int* ibsum = icsr + N_EDGES;               // [391]

    const int M = N_NODES;
    const int gGemm = (M + 63) / 64;           // 1563
    const int gEdge = (N_EDGES + 255) / 256;   // 3125
    const int gNode = NB_SCAN;                 // 391

    // ---- 1: weight transposes + zero ideg + zero pooled ----
    wt_all_k<<<903, 256, 0, stream>>>(w1a, w1b, w2a, w2b, w3a, w3b,
                                      wt1a, wt1b, wt2a, wt2b, wt3a, wt3b,
                                      ideg, pooled);

    // ---- 2: gemm1 (async dbuf) + histogram ----
    gemm1_hist_k<<<G1_BLOCKS + HIST_BLOCKS, 256, 0, stream>>>(x, wt1a, Y, M, dst, ideg);

    // ---- 3-5: scan chain + fill ----
    scan1_k<<<gNode, 256, 0, stream>>>(ideg, itmp, ibsum);
    scan23_k<<<gNode, 256, 0, stream>>>(itmp, ideg, ibsum, irow);
    fill_k<<<gEdge, 256, 0, stream>>>(src, dst, irow, icsr);

    // ---- 6-8: fused layers ----
    gather_mlp_k<false><<<gGemm, 256, 0, stream>>>(
        Y, icsr, irow, ideg, eps1, b1a, g1, be1, m1, v1,
        wt1b, b1b, wt2a, H, nullptr, nullptr, M);
    gather_mlp_k<false><<<gGemm, 256, 0, stream>>>(
        H, icsr, irow, ideg, eps2, b2a, g2, be2, m2, v2,
        wt2b, b2b, wt3a, Y, nullptr, nullptr, M);
    gather_mlp_k<true><<<gGemm, 256, 0, stream>>>(
        Y, icsr, irow, ideg, eps3, b3a, g3, be3, m3, v3,
        wt3b, b3b, nullptr, nullptr, batch, pooled, M);

    // ---- 9: classifier ----
    classifier_k<<<1, 256, 0, stream>>>(pooled, wc, bc, out);
}

// Round 14
// 344.892 us; speedup vs baseline: 1.2449x; 1.0255x over previous
//
#include <hip/hip_runtime.h>
#include <hip/hip_bf16.h>

// GIN classifier. R13: gemm1 rebuilt as TRUE counted-vmcnt stream (T3+T4):
// both A and B staged via global_load_lds (no mid-phase VMEM -> FIFO-safe
// counted waits), NBUF=4, stage-ahead 2, vmcnt(8) steady (never 0 mid-loop),
// raw s_barrier per phase, XOR-swizzled tiles. Rest frozen from R12.

#define N_NODES 100000
#define N_EDGES 800000
#define N_GRAPHS 128
#define NB_SCAN 391   // ceil(N_NODES/256)
#define LDP 136       // bf16 LDS row stride: 2-way bank alias only (free)
#define FLDP 68       // f32 row stride for pool staging
#define G1_BLOCKS 1563
#define HIST_BLOCKS 782   // 782*1024 >= 800000

typedef __bf16 bf16x8 __attribute__((ext_vector_type(8)));
typedef float f32x4 __attribute__((ext_vector_type(4)));
typedef unsigned short ushort_t;
typedef unsigned int uint_t;

static __device__ __forceinline__ ushort_t f2b(float f) {
    uint_t u = __builtin_bit_cast(uint_t, f);
    uint_t r = (u + 0x7fffu + ((u >> 16) & 1u)) >> 16;   // RNE
    return (ushort_t)r;
}
static __device__ __forceinline__ float b2f(ushort_t u) {
    return __builtin_bit_cast(float, (uint_t)u << 16);
}

static __device__ __forceinline__ void gload16(const void* gp, void* lp) {
    __builtin_amdgcn_global_load_lds(
        (const __attribute__((address_space(1))) void*)gp,
        (__attribute__((address_space(3))) void*)lp, 16, 0, 0);
}

// ---- weight transposes + zero ideg + zero pooled, one dispatch -------------
__global__ __launch_bounds__(256) void wt_all_k(
        const float* __restrict__ w1a, const float* __restrict__ w1b,
        const float* __restrict__ w2a, const float* __restrict__ w2b,
        const float* __restrict__ w3a, const float* __restrict__ w3b,
        ushort_t* __restrict__ o1a, ushort_t* __restrict__ o1b,
        ushort_t* __restrict__ o2a, ushort_t* __restrict__ o2b,
        ushort_t* __restrict__ o3a, ushort_t* __restrict__ o3b,
        int* __restrict__ ideg, float* __restrict__ pooled) {
    int t = blockIdx.x * 256 + threadIdx.x;
    if (t < 122880) {
        const float* W; ushort_t* O; int K, N, i;
        if      (t <  49152) { W = w1a; O = o1a; K = 384; N = 128; i = t; }
        else if (t <  65536) { W = w1b; O = o1b; K = 128; N = 128; i = t - 49152; }
        else if (t <  81920) { W = w2a; O = o2a; K = 128; N = 128; i = t - 65536; }
        else if (t <  98304) { W = w2b; O = o2b; K = 128; N = 128; i = t - 81920; }
        else if (t < 114688) { W = w3a; O = o3a; K = 128; N = 128; i = t - 98304; }
        else                 { W = w3b; O = o3b; K = 128; N = 64;  i = t - 114688; }
        int k = i / N, c = i % N;
        O[c * K + k] = f2b(W[i]);
    } else if (t < 222880) {
        ideg[t - 122880] = 0;
    } else if (t < 231072) {
        pooled[t - 222880] = 0.f;
    }
}

// ---- mega dispatch: gemm1 (counted-vmcnt stream) + CSR histogram -----------
// gemm1: C[M,128] = bf16(A fp32 [M,384]) @ Wt. BM=64, BK=32, 12 phases.
// A tiles fp32 8KB, B tiles bf16 8KB, NBUF=4 each (64 KB), stage-ahead 2.
__global__ __launch_bounds__(256) void gemm1_hist_k(const float* __restrict__ A,
                                                    const ushort_t* __restrict__ Wt,
                                                    ushort_t* __restrict__ C, int M,
                                                    const int* __restrict__ dst,
                                                    int* __restrict__ deg) {
    __shared__ __align__(16) float    Af[4][2048];   // 4 x 8 KB (64 rows x 32 k)
    __shared__ __align__(16) ushort_t Bl[4][4096];   // 4 x 8 KB (128 cols x 32 k)

    if (blockIdx.x >= G1_BLOCKS) {
        int b = blockIdx.x - G1_BLOCKS;
        int e0 = b * 1024 + threadIdx.x;
        #pragma unroll
        for (int p = 0; p < 4; ++p) {
            int e = e0 + p * 256;
            if (e < N_EDGES) atomicAdd(&deg[dst[e]], 1);
        }
        return;
    }

    constexpr int K = 384;
    const int tid  = threadIdx.x;
    const int lane = tid & 63;
    const int wid  = tid >> 6;
    const int wrow = wid >> 1;
    const int wcol = wid & 1;
    const int l15  = lane & 15;
    const int kg   = lane >> 4;
    const int row0 = blockIdx.x * 64;

    // A staging geometry: units U=tid (rows 0..31), U+256 (rows 32..63).
    // unit U -> row R=U>>3, col-unit c=U&7; source pre-swizzled c^(R&7).
    const int R0 = tid >> 3, cu = tid & 7;
    const int R1 = R0 + 32;
    int gr0 = row0 + R0; if (gr0 > M - 1) gr0 = M - 1;
    int gr1 = row0 + R1; if (gr1 > M - 1) gr1 = M - 1;
    const int as0 = (cu ^ (R0 & 7)) * 4;     // float offset in k-tile
    const int as1 = (cu ^ (R1 & 7)) * 4;
    // B staging geometry: units V=tid (cols 0..63), V+256 (cols 64..127).
    // unit V -> col=V>>2, u=V&3; source pre-swizzled u^(col&3).
    const int col0 = tid >> 2, bu = tid & 3;
    const int col1 = col0 + 64;
    const int bs0 = (bu ^ (col0 & 3)) * 8;   // ushort offset in col's k-tile
    const int bs1 = (bu ^ (col1 & 3)) * 8;

    f32x4 acc[2][4];
    #pragma unroll
    for (int i = 0; i < 2; ++i)
        #pragma unroll
        for (int j = 0; j < 4; ++j)
            acc[i][j] = f32x4{0.f, 0.f, 0.f, 0.f};

    // prologue: stage tiles 0,1 (8 load-instr outstanding per wave)
    #pragma unroll
    for (int p = 0; p < 2; ++p) {
        int k0 = p * 32;
        gload16(A + (size_t)gr0 * K + k0 + as0, &Af[p][wid * 256]);
        gload16(A + (size_t)gr1 * K + k0 + as1, &Af[p][1024 + wid * 256]);
        gload16(Wt + (size_t)col0 * K + k0 + bs0, &Bl[p][wid * 512]);
        gload16(Wt + (size_t)col1 * K + k0 + bs1, &Bl[p][2048 + wid * 512]);
    }

    const int rA0 = wrow * 32 + l15;
    const int rA1 = rA0 + 16;
    const int sw0 = rA0 & 7;                 // == rA1 & 7

    #pragma unroll
    for (int t = 0; t < 12; ++t) {
        if (t + 2 < 12) {
            int k0 = (t + 2) * 32;
            int buf = (t + 2) & 3;
            gload16(A + (size_t)gr0 * K + k0 + as0, &Af[buf][wid * 256]);
            gload16(A + (size_t)gr1 * K + k0 + as1, &Af[buf][1024 + wid * 256]);
            gload16(Wt + (size_t)col0 * K + k0 + bs0, &Bl[buf][wid * 512]);
            gload16(Wt + (size_t)col1 * K + k0 + bs1, &Bl[buf][2048 + wid * 512]);
        }
        if (t < 10)       asm volatile("s_waitcnt vmcnt(8)" ::: "memory");
        else if (t == 10) asm volatile("s_waitcnt vmcnt(4)" ::: "memory");
        else              asm volatile("s_waitcnt vmcnt(0)" ::: "memory");
        __builtin_amdgcn_s_barrier();
        __builtin_amdgcn_sched_barrier(0);

        const float*    Ab = Af[t & 3];
        const ushort_t* Bb = Bl[t & 3];
        float4 lo0 = *reinterpret_cast<const float4*>(Ab + rA0 * 32 + (((kg * 2)     ^ sw0) * 4));
        float4 hi0 = *reinterpret_cast<const float4*>(Ab + rA0 * 32 + (((kg * 2 + 1) ^ sw0) * 4));
        float4 lo1 = *reinterpret_cast<const float4*>(Ab + rA1 * 32 + (((kg * 2)     ^ sw0) * 4));
        float4 hi1 = *reinterpret_cast<const float4*>(Ab + rA1 * 32 + (((kg * 2 + 1) ^ sw0) * 4));
        bf16x8 a0, a1;
        a0[0] = (__bf16)lo0.x; a0[1] = (__bf16)lo0.y; a0[2] = (__bf16)lo0.z; a0[3] = (__bf16)lo0.w;
        a0[4] = (__bf16)hi0.x; a0[5] = (__bf16)hi0.y; a0[6] = (__bf16)hi0.z; a0[7] = (__bf16)hi0.w;
        a1[0] = (__bf16)lo1.x; a1[1] = (__bf16)lo1.y; a1[2] = (__bf16)lo1.z; a1[3] = (__bf16)lo1.w;
        a1[4] = (__bf16)hi1.x; a1[5] = (__bf16)hi1.y; a1[6] = (__bf16)hi1.z; a1[7] = (__bf16)hi1.w;
        #pragma unroll
        for (int j = 0; j < 4; ++j) {
            int col = wcol * 64 + j * 16 + l15;
            bf16x8 b = *reinterpret_cast<const bf16x8*>(Bb + col * 32 + ((kg ^ (col & 3)) * 8));
            acc[0][j] = __builtin_amdgcn_mfma_f32_16x16x32_bf16(a0, b, acc[0][j], 0, 0, 0);
            acc[1][j] = __builtin_amdgcn_mfma_f32_16x16x32_bf16(a1, b, acc[1][j], 0, 0, 0);
        }
    }

    // epilogue: stage bf16 rows in LDS (reuse Af), full-line coalesced store
    __syncthreads();
    ushort_t* Es = (ushort_t*)&Af[0][0];
    #pragma unroll
    for (int i = 0; i < 2; ++i)
        #pragma unroll
        for (int j = 0; j < 4; ++j) {
            int col = wcol * 64 + j * 16 + l15;
            #pragma unroll
            for (int q = 0; q < 4; ++q) {
                int row = wrow * 32 + i * 16 + kg * 4 + q;
                Es[row * LDP + col] = f2b(acc[i][j][q]);
            }
        }
    __syncthreads();
    #pragma unroll
    for (int p = 0; p < 4; ++p) {
        int idx = tid + p * 256;
        int rr = idx >> 4, c16 = idx & 15;
        int gr = row0 + rr;
        if (gr < M)
            *reinterpret_cast<uint4*>(C + (size_t)gr * 128 + c16 * 8) =
                *reinterpret_cast<const uint4*>(&Es[rr * LDP + c16 * 8]);
    }
}

// ---------------- CSR scan chain ----------------
__global__ __launch_bounds__(256) void scan1_k(const int* __restrict__ deg,
                                               int* __restrict__ tmp,
                                               int* __restrict__ bsum) {
    __shared__ int s[256];
    int i = blockIdx.x * 256 + threadIdx.x;
    int t = threadIdx.x;
    s[t] = (i < N_NODES) ? deg[i] : 0;
    __syncthreads();
    for (int off = 1; off < 256; off <<= 1) {
        int v = (t >= off) ? s[t - off] : 0;
        __syncthreads();
        s[t] += v;
        __syncthreads();
    }
    if (i < N_NODES) tmp[i] = s[t];
    if (t == 255) bsum[blockIdx.x] = s[255];
}

__global__ __launch_bounds__(256) void scan23_k(const int* __restrict__ tmp,
                                                const int* __restrict__ deg,
                                                const int* __restrict__ bsum,
                                                int* __restrict__ row_start) {
    __shared__ int sb[256];
    int t = threadIdx.x;
    int partial = 0;
    for (int i = t; i < (int)blockIdx.x; i += 256) partial += bsum[i];
    sb[t] = partial;
    __syncthreads();
    for (int off = 128; off > 0; off >>= 1) {
        if (t < off) sb[t] += sb[t + off];
        __syncthreads();
    }
    int boff = sb[0];
    int i = blockIdx.x * 256 + t;
    if (i < N_NODES) row_start[i] = tmp[i] - deg[i] + boff;
}

__global__ __launch_bounds__(256) void fill_k(const int* __restrict__ src,
                                              const int* __restrict__ dst,
                                              int* __restrict__ row_start,
                                              int* __restrict__ csr_src) {
    int e = blockIdx.x * 256 + threadIdx.x;
    if (e >= N_EDGES) return;
    int idx = atomicAdd(&row_start[dst[e]], 1);
    csr_src[idx] = src[e];
}

// ======== fused layer: gather+BN+ReLU -> LDS -> GEMM1(+b,relu) ->
//          [TAIL: pool]  or  [GEMM2 -> Yout] ================================
template<bool TAIL>
__global__ __launch_bounds__(256) void gather_mlp_k(
        const ushort_t* __restrict__ Yin,
        const int* __restrict__ csr, const int* __restrict__ rend,
        const int* __restrict__ deg,
        const float* __restrict__ epsp, const float* __restrict__ ba,
        const float* __restrict__ g, const float* __restrict__ be,
        const float* __restrict__ mm, const float* __restrict__ vv,
        const ushort_t* __restrict__ Wb, const float* __restrict__ bias1,
        const ushort_t* __restrict__ Wa2,
        ushort_t* __restrict__ Yout,
        const int* __restrict__ batch, float* __restrict__ pooled, int M) {
    constexpr int NJ1 = TAIL ? 2 : 4;       // N1 = 64 or 128
    __shared__ ushort_t Hl[64 * LDP];
    __shared__ ushort_t Xl[64 * LDP];       // f32 pool staging view for TAIL
    float* Fl = (float*)Xl;

    const int tid  = threadIdx.x;
    const int lane = tid & 63;
    const int wid  = tid >> 6;
    const int l15  = lane & 15;
    const int slot = lane >> 4;
    const int c0   = l15 * 8;
    const int row0 = blockIdx.x * 64;

    // ---- phase G: gather + BN + ReLU -> Hl (wave w owns rows w*16..w*16+15)
    {
        float ep = 1.0f + epsp[0];
        float sc[8], sh[8];
        #pragma unroll
        for (int jj = 0; jj < 8; ++jj) {
            int c = c0 + jj;
            float s = g[c] * rsqrtf(vv[c] + 1e-5f);
            sc[jj] = s;
            sh[jj] = (ba[c] - mm[c]) * s + be[c];
        }

        const int base = row0 + wid * 16;
        int cn = base; if (cn > M - 1) cn = M - 1;
        int end = rend[cn], d = deg[cn];
        int st = end - d;
        int nlim = (d > 64) ? 64 : d;
        int nb = (lane < nlim) ? csr[st + lane] : 0;

        for (int nl = 0; nl < 16; ++nl) {
            int node = base + nl; if (node > M - 1) node = M - 1;
            int nxt = base + nl + 1; if (nxt > M - 1) nxt = M - 1;
            int nend = 0, nd = 0;
            if (nl < 15) { nend = rend[nxt]; nd = deg[nxt]; }   // prefetch meta

            uint4 ow = *reinterpret_cast<const uint4*>(Yin + (size_t)node * 128 + c0);

            float acc[8] = {0.f, 0.f, 0.f, 0.f, 0.f, 0.f, 0.f, 0.f};
            for (int j0 = 0; j0 < nlim; j0 += 8) {
                int jA = j0 + slot;
                int jB = j0 + 4 + slot;
                int ia = __shfl(nb, jA & 63);
                int ib = __shfl(nb, jB & 63);
                uint4 wa = *reinterpret_cast<const uint4*>(Yin + (size_t)ia * 128 + c0);
                uint4 wb = *reinterpret_cast<const uint4*>(Yin + (size_t)ib * 128 + c0);
                float fa = (jA < nlim) ? 1.f : 0.f;
                float fb = (jB < nlim) ? 1.f : 0.f;
                uint_t ua[4] = {wa.x, wa.y, wa.z, wa.w};
                uint_t ub[4] = {wb.x, wb.y, wb.z, wb.w};
                #pragma unroll
                for (int p = 0; p < 4; ++p) {
                    acc[2 * p]     += fa * b2f((ushort_t)(ua[p] & 0xffff));
                    acc[2 * p + 1] += fa * b2f((ushort_t)(ua[p] >> 16));
                    acc[2 * p]     += fb * b2f((ushort_t)(ub[p] & 0xffff));
                    acc[2 * p + 1] += fb * b2f((ushort_t)(ub[p] >> 16));
                }
            }
            for (int j = st + 64; j < end; ++j) {
                if (slot == 0) {
                    int idx = csr[j];
                    uint4 w = *reinterpret_cast<const uint4*>(Yin + (size_t)idx * 128 + c0);
                    uint_t uw[4] = {w.x, w.y, w.z, w.w};
                    #pragma unroll
                    for (int p = 0; p < 4; ++p) {
                        acc[2 * p]     += b2f((ushort_t)(uw[p] & 0xffff));
                        acc[2 * p + 1] += b2f((ushort_t)(uw[p] >> 16));
                    }
                }
            }

            // prefetch next node's indices (overlaps reduce + BN + LDS write)
            int nst = nend - nd;
            int nnlim = (nd > 64) ? 64 : nd;
            int nb2 = 0;
            if (nl < 15 && lane < nnlim) nb2 = csr[nst + lane];

            #pragma unroll
            for (int jj = 0; jj < 8; ++jj) {
                acc[jj] += __shfl_xor(acc[jj], 16);
                acc[jj] += __shfl_xor(acc[jj], 32);
            }
            uint_t uo[4] = {ow.x, ow.y, ow.z, ow.w};
            ushort_t rr[8];
            #pragma unroll
            for (int p = 0; p < 4; ++p) {
                float o0 = b2f((ushort_t)(uo[p] & 0xffff));
                float o1 = b2f((ushort_t)(uo[p] >> 16));
                float t0 = sc[2 * p] * (ep * o0 + acc[2 * p]) + sh[2 * p];
                float t1 = sc[2 * p + 1] * (ep * o1 + acc[2 * p + 1]) + sh[2 * p + 1];
                rr[2 * p]     = f2b(fmaxf(t0, 0.f));
                rr[2 * p + 1] = f2b(fmaxf(t1, 0.f));
            }
            if (slot == 0) {
                uint4 packed;
                packed.x = (uint_t)rr[0] | ((uint_t)rr[1] << 16);
                packed.y = (uint_t)rr[2] | ((uint_t)rr[3] << 16);
                packed.z = (uint_t)rr[4] | ((uint_t)rr[5] << 16);
                packed.w = (uint_t)rr[6] | ((uint_t)rr[7] << 16);
                *reinterpret_cast<uint4*>(&Hl[(wid * 16 + nl) * LDP + c0]) = packed;
            }

            end = nend; d = nd; st = nst; nlim = nnlim; nb = nb2;
        }
    }
    __syncthreads();

    // ---- MLP phase ----
    const int wrow = wid >> 1;
    const int wcol = wid & 1;
    const int kg   = lane >> 4;

    f32x4 acc1[2][NJ1];
    #pragma unroll
    for (int i = 0; i < 2; ++i)
        #pragma unroll
        for (int j = 0; j < NJ1; ++j)
            acc1[i][j] = f32x4{0.f, 0.f, 0.f, 0.f};
    #pragma unroll
    for (int kk = 0; kk < 4; ++kk) {
        bf16x8 a0 = *reinterpret_cast<const bf16x8*>(&Hl[(wrow * 32 + l15) * LDP + kk * 32 + kg * 8]);
        bf16x8 a1 = *reinterpret_cast<const bf16x8*>(&Hl[(wrow * 32 + 16 + l15) * LDP + kk * 32 + kg * 8]);
        #pragma unroll
        for (int j = 0; j < NJ1; ++j) {
            int col = wcol * (16 * NJ1) + j * 16 + l15;
            bf16x8 b = *reinterpret_cast<const bf16x8*>(Wb + (size_t)col * 128 + kk * 32 + kg * 8);
            acc1[0][j] = __builtin_amdgcn_mfma_f32_16x16x32_bf16(a0, b, acc1[0][j], 0, 0, 0);
            acc1[1][j] = __builtin_amdgcn_mfma_f32_16x16x32_bf16(a1, b, acc1[1][j], 0, 0, 0);
        }
    }

    if constexpr (TAIL) {
        #pragma unroll
        for (int i = 0; i < 2; ++i)
            #pragma unroll
            for (int j = 0; j < NJ1; ++j) {
                int col = wcol * 32 + j * 16 + l15;
                float bi = bias1[col];
                #pragma unroll
                for (int q = 0; q < 4; ++q) {
                    int row = wrow * 32 + i * 16 + kg * 4 + q;
                    Fl[row * FLDP + col] = fmaxf(acc1[i][j][q] + bi, 0.f);
                }
            }
        __syncthreads();
        int col = tid & 63;
        int qq  = tid >> 6;
        float a = 0.f;
        int cur = -1;
        for (int rr2 = 0; rr2 < 16; ++rr2) {
            int r = qq * 16 + rr2;
            int gr = row0 + r;
            if (gr >= M) break;
            int b = batch[gr];
            if (b != cur) {
                if (cur >= 0) atomicAdd(&pooled[cur * 64 + col], a);
                a = 0.f;
                cur = b;
            }
            a += Fl[r * FLDP + col];
        }
        if (cur >= 0) atomicAdd(&pooled[cur * 64 + col], a);
    } else {
        #pragma unroll
        for (int i = 0; i < 2; ++i)
            #pragma unroll
            for (int j = 0; j < NJ1; ++j) {
                int col = wcol * 64 + j * 16 + l15;
                float bi = bias1[col];
                #pragma unroll
                for (int q = 0; q < 4; ++q) {
                    int row = wrow * 32 + i * 16 + kg * 4 + q;
                    Xl[row * LDP + col] = f2b(fmaxf(acc1[i][j][q] + bi, 0.f));
                }
            }
        __syncthreads();

        f32x4 acc2[2][4];
        #pragma unroll
        for (int i = 0; i < 2; ++i)
            #pragma unroll
            for (int j = 0; j < 4; ++j)
                acc2[i][j] = f32x4{0.f, 0.f, 0.f, 0.f};
        #pragma unroll
        for (int kk = 0; kk < 4; ++kk) {
            bf16x8 a0 = *reinterpret_cast<const bf16x8*>(&Xl[(wrow * 32 + l15) * LDP + kk * 32 + kg * 8]);
            bf16x8 a1 = *reinterpret_cast<const bf16x8*>(&Xl[(wrow * 32 + 16 + l15) * LDP + kk * 32 + kg * 8]);
            #pragma unroll
            for (int j = 0; j < 4; ++j) {
                int col = wcol * 64 + j * 16 + l15;
                bf16x8 b = *reinterpret_cast<const bf16x8*>(Wa2 + (size_t)col * 128 + kk * 32 + kg * 8);
                acc2[0][j] = __builtin_amdgcn_mfma_f32_16x16x32_bf16(a0, b, acc2[0][j], 0, 0, 0);
                acc2[1][j] = __builtin_amdgcn_mfma_f32_16x16x32_bf16(a1, b, acc2[1][j], 0, 0, 0);
            }
        }
        __syncthreads();   // Hl reads (GEMM1) done; reuse Hl for output staging
        #pragma unroll
        for (int i = 0; i < 2; ++i)
            #pragma unroll
            for (int j = 0; j < 4; ++j) {
                int col = wcol * 64 + j * 16 + l15;
                #pragma unroll
                for (int q = 0; q < 4; ++q) {
                    int row = wrow * 32 + i * 16 + kg * 4 + q;
                    Hl[row * LDP + col] = f2b(acc2[i][j][q]);
                }
            }
        __syncthreads();
        #pragma unroll
        for (int p = 0; p < 4; ++p) {
            int idx = tid + p * 256;
            int r = idx >> 4, c16 = idx & 15;
            int gr = row0 + r;
            if (gr < M)
                *reinterpret_cast<uint4*>(Yout + (size_t)gr * 128 + c16 * 8) =
                    *reinterpret_cast<const uint4*>(&Hl[r * LDP + c16 * 8]);
        }
    }
}

// ---------------- classifier ----------------
__global__ __launch_bounds__(256) void classifier_k(const float* __restrict__ pooled,
                                                    const float* __restrict__ wc,
                                                    const float* __restrict__ bc,
                                                    float* __restrict__ out) {
    int t = threadIdx.x;
    int gidx = t >> 1, c = t & 1;
    float s = bc[c];
    #pragma unroll
    for (int k = 0; k < 64; ++k)
        s += pooled[gidx * 64 + k] * wc[k * 2 + c];
    out[gidx * 2 + c] = s;
}

extern "C" void kernel_launch(void* const* d_in, const int* in_sizes, int n_in,
                              void* d_out, int out_size, void* d_ws, size_t ws_size,
                              hipStream_t stream) {
    const float* x     = (const float*)d_in[0];
    const int*   ei    = (const int*)d_in[1];
    const int*   src   = ei;
    const int*   dst   = ei + N_EDGES;
    const int*   batch = (const int*)d_in[2];
    const float* eps1 = (const float*)d_in[3];
    const float* w1a  = (const float*)d_in[4];
    const float* b1a  = (const float*)d_in[5];
    const float* g1   = (const float*)d_in[6];
    const float* be1  = (const float*)d_in[7];
    const float* m1   = (const float*)d_in[8];
    const float* v1   = (const float*)d_in[9];
    const float* w1b  = (const float*)d_in[10];
    const float* b1b  = (const float*)d_in[11];
    const float* eps2 = (const float*)d_in[12];
    const float* w2a  = (const float*)d_in[13];
    const float* b2a  = (const float*)d_in[14];
    const float* g2   = (const float*)d_in[15];
    const float* be2  = (const float*)d_in[16];
    const float* m2   = (const float*)d_in[17];
    const float* v2   = (const float*)d_in[18];
    const float* w2b  = (const float*)d_in[19];
    const float* b2b  = (const float*)d_in[20];
    const float* eps3 = (const float*)d_in[21];
    const float* w3a  = (const float*)d_in[22];
    const float* b3a  = (const float*)d_in[23];
    const float* g3   = (const float*)d_in[24];
    const float* be3  = (const float*)d_in[25];
    const float* m3   = (const float*)d_in[26];
    const float* v3   = (const float*)d_in[27];
    const float* w3b  = (const float*)d_in[28];
    const float* b3b  = (const float*)d_in[29];
    const float* wc   = (const float*)d_in[30];
    const float* bc   = (const float*)d_in[31];
    float* out = (float*)d_out;

    // workspace layout
    ushort_t* Y = (ushort_t*)d_ws;             // [100000,128] bf16
    ushort_t* H = Y + 12800000;                // [100000,128] bf16 (ping-pong)
    ushort_t* wt1a = H + 12800000;             // 384*128
    ushort_t* wt1b = wt1a + 49152;             // 128*128
    ushort_t* wt2a = wt1b + 16384;
    ushort_t* wt2b = wt2a + 16384;
    ushort_t* wt3a = wt2b + 16384;
    ushort_t* wt3b = wt3a + 16384;             // 64*128
    float* pooled = (float*)(wt3b + 8192);     // [128,64]
    int* ideg = (int*)(pooled + 8192);         // [100000]
    int* irow = ideg + N_NODES;
    int* itmp = irow + N_NODES;
    int* icsr = itmp + N_NODES;                // [800000]
    int* ibsum = icsr + N_EDGES;               // [391]

    const int M = N_NODES;
    const int gGemm = (M + 63) / 64;           // 1563
    const int gEdge = (N_EDGES + 255) / 256;   // 3125
    const int gNode = NB_SCAN;                 // 391

    // ---- 1: weight transposes + zero ideg + zero pooled ----
    wt_all_k<<<903, 256, 0, stream>>>(w1a, w1b, w2a, w2b, w3a, w3b,
                                      wt1a, wt1b, wt2a, wt2b, wt3a, wt3b,
                                      ideg, pooled);

    // ---- 2: gemm1 (counted-vmcnt stream) + histogram ----
    gemm1_hist_k<<<G1_BLOCKS + HIST_BLOCKS, 256, 0, stream>>>(x, wt1a, Y, M, dst, ideg);

    // ---- 3-5: scan chain + fill ----
    scan1_k<<<gNode, 256, 0, stream>>>(ideg, itmp, ibsum);
    scan23_k<<<gNode, 256, 0, stream>>>(itmp, ideg, ibsum, irow);
    fill_k<<<gEdge, 256, 0, stream>>>(src, dst, irow, icsr);

    // ---- 6-8: fused layers ----
    gather_mlp_k<false><<<gGemm, 256, 0, stream>>>(
        Y, icsr, irow, ideg, eps1, b1a, g1, be1, m1, v1,
        wt1b, b1b, wt2a, H, nullptr, nullptr, M);
    gather_mlp_k<false><<<gGemm, 256, 0, stream>>>(
        H, icsr, irow, ideg, eps2, b2a, g2, be2, m2, v2,
        wt2b, b2b, wt3a, Y, nullptr, nullptr, M);
    gather_mlp_k<true><<<gGemm, 256, 0, stream>>>(
        Y, icsr, irow, ideg, eps3, b3a, g3, be3, m3, v3,
        wt3b, b3b, nullptr, nullptr, batch, pooled, M);

    // ---- 9: classifier ----
    classifier_k<<<1, 256, 0, stream>>>(pooled, wc, bc, out);
}